// Round 5
// baseline (452.516 us; speedup 1.0000x reference)
//
#include <hip/hip_runtime.h>
#include <hip/hip_bf16.h>
#include <math.h>

static constexpr int kN   = 50000;   // nodes
static constexpr int kE   = 800000;  // edges
static constexpr int kHID = 256;
static constexpr int kHD  = 32;

typedef short bf16x8 __attribute__((ext_vector_type(8)));
typedef float f32x4  __attribute__((ext_vector_type(4)));
typedef float f32x2  __attribute__((ext_vector_type(2)));
typedef unsigned short us8 __attribute__((ext_vector_type(8)));
typedef unsigned int u32x4 __attribute__((ext_vector_type(4)));
typedef int i32x2 __attribute__((ext_vector_type(2)));
typedef int i32x4 __attribute__((ext_vector_type(4)));

__device__ __forceinline__ float b2f(unsigned short u) {
  union { unsigned v; float f; } c; c.v = ((unsigned)u) << 16; return c.f;
}

__device__ __forceinline__ unsigned short f2bu(float f) {
  __hip_bfloat16 b = __float2bfloat16(f);
  union { __hip_bfloat16 b; unsigned short u; } c; c.b = b; return c.u;
}

// unpack u32 holding 2 bf16 (channels 2j, 2j+1) into f32x2
__device__ __forceinline__ f32x2 bf2up(unsigned u) {
  union { unsigned v; float f; } lo, hi;
  lo.v = u << 16; hi.v = u & 0xffff0000u;
  return f32x2{lo.f, hi.f};
}

// quad-local butterfly add via DPP (no LDS round-trip).
__device__ __forceinline__ float quad_add_xor1(float s) {
  union { float f; int i; } a, b;
  a.f = s;
  b.i = __builtin_amdgcn_mov_dpp(a.i, 0xB1, 0xF, 0xF, true);  // quad_perm [1,0,3,2]
  return s + b.f;
}
__device__ __forceinline__ float quad_add_xor2(float s) {
  union { float f; int i; } a, b;
  a.f = s;
  b.i = __builtin_amdgcn_mov_dpp(a.i, 0x4E, 0xF, 0xF, true);  // quad_perm [2,3,0,1]
  return s + b.f;
}

// global -> LDS async copy, 16 B per lane; LDS dest = uniform base + lane*16
__device__ __forceinline__ void load_lds16(const void* g, void* l) {
  __builtin_amdgcn_global_load_lds(
      (const __attribute__((address_space(1))) unsigned int*)(unsigned long long)(uintptr_t)g,
      (__attribute__((address_space(3))) unsigned int*)(unsigned int)(uintptr_t)l,
      16, 0, 0);
}

// ---------------------------------------------------------------------------
// h -> bf16, 8 elements/thread (vectorized loads + 16B stores)
// ---------------------------------------------------------------------------
__global__ void split_h_kernel(const float* __restrict__ h,
                               __hip_bfloat16* __restrict__ Ah) {
  int idx = blockIdx.x * 256 + threadIdx.x;   // N*256/8 threads exactly
  const f32x4* hp = (const f32x4*)(h + (size_t)idx * 8);
  f32x4 a = hp[0], b = hp[1];
  us8 o;
  o[0] = f2bu(a[0]); o[1] = f2bu(a[1]); o[2] = f2bu(a[2]); o[3] = f2bu(a[3]);
  o[4] = f2bu(b[0]); o[5] = f2bu(b[1]); o[6] = f2bu(b[2]); o[7] = f2bu(b[3]);
  *(us8*)(Ah + (size_t)idx * 8) = o;
}

// ---------------------------------------------------------------------------
// Build Bt[768][256] bf16 (B transposed, n-major) + biasP[768] fp32.
// n: 0-255 q, 256-511 k, 512-767 v; channel permuted cc=h*32+d <- c=d*8+h,
// softmax scaling folded into the q group (weights AND bias).
// ---------------------------------------------------------------------------
__global__ void build_bt_kernel(const float* __restrict__ Wq, const float* __restrict__ bq,
                                const float* __restrict__ Wk, const float* __restrict__ bk,
                                const float* __restrict__ Wv, const float* __restrict__ bv,
                                __hip_bfloat16* __restrict__ Bt, float* __restrict__ biasP) {
  const int n  = blockIdx.x;          // 0..767
  const int kk = threadIdx.x;         // 0..255
  const int g  = n >> 8;
  const int cc = n & 255;
  const int c  = ((cc & 31) << 3) + (cc >> 5);     // ref channel d*8+h
  const float scale = (g == 0) ? 0.17677669529663689f : 1.0f;  // HD^-0.5
  const float* W = (g == 0) ? Wq : ((g == 1) ? Wk : Wv);
  Bt[n * 256 + kk] = __float2bfloat16(W[kk * 256 + c] * scale);
  if (kk == 0) {
    const float* b = (g == 0) ? bq : ((g == 1) ? bk : bv);
    biasP[n] = b[c] * scale;
  }
}

// ---------------------------------------------------------------------------
// Fused prep: blocks 0..195 build row_ptr (lower_bound over sorted edge_rows);
// blocks 196.. pack (col_ind, val) into interleaved int2 cv[] (one dwordx2
// per edge in the attention loop instead of two dword loads).
// ---------------------------------------------------------------------------
__global__ void prep_kernel(const int* __restrict__ er, int* __restrict__ rp,
                            const int* __restrict__ ci, const float* __restrict__ vl,
                            i32x2* __restrict__ cv) {
  const int b = blockIdx.x;
  if (b < 196) {
    int i = b * 256 + threadIdx.x;
    if (i > kN) return;
    int lo = 0, hi = kE;
    while (lo < hi) {
      int mid = (lo + hi) >> 1;
      if (er[mid] < i) lo = mid + 1; else hi = mid;
    }
    rp[i] = lo;
  } else {
    const int e4 = ((b - 196) * 256 + threadIdx.x) * 4;
    if (e4 < kE) {
      i32x4 c = *(const i32x4*)(ci + e4);
      f32x4 w = *(const f32x4*)(vl + e4);
      i32x4 o0 = {c[0], __float_as_int(w[0]), c[1], __float_as_int(w[1])};
      i32x4 o1 = {c[2], __float_as_int(w[2]), c[3], __float_as_int(w[3])};
      *(i32x4*)(cv + e4)     = o0;
      *(i32x4*)(cv + e4 + 2) = o1;
    }
  }
}

// ---------------------------------------------------------------------------
// Fused MFMA GEMM: C[M=50000][768] = A[M][256] * Bt[768][256]^T + bias.
// 128x128 tile, BK=64, 256 threads (4 waves 2x2), global_load_lds staging,
// XOR-swizzled LDS (conflict-free). 1-D grid with XCD-aware decode: all 6
// N-tiles sharing an A-panel land on the SAME XCD consecutively (A in L2).
// Epilogue: C tile staged bf16 in LDS (padded), stored as coalesced 16B chunks.
// ---------------------------------------------------------------------------
__global__ __launch_bounds__(256) void gemm_qkv_kernel(
    const __hip_bfloat16* __restrict__ Ah,
    const __hip_bfloat16* __restrict__ Bt, const float* __restrict__ biasP,
    __hip_bfloat16* __restrict__ qb, __hip_bfloat16* __restrict__ kvb) {
  __shared__ __align__(16) char smemRaw[34816];   // max(32 KB tiles, 128*136*2 C)
  short* smemA = (short*)smemRaw;                 // [128][64] 16B-chunk swizzled
  short* smemB = (short*)(smemRaw + 16384);
  short* smemC = (short*)smemRaw;                 // [128][136] padded C tile

  // XCD-aware decode: L = xcd + 8*(n + 6*mg), m-tile = mg*8 + xcd
  const int L   = blockIdx.x;
  const int xcd = L & 7;
  const int t   = L >> 3;
  const int nt  = t % 6;
  const int mg  = t / 6;
  const int mt  = mg * 8 + xcd;
  if (mt >= 391) return;
  const int colBase = nt * 128;
  const int rowBase = mt * 128;

  const int tid  = threadIdx.x;
  const int wave = tid >> 6;
  const int lane = tid & 63;
  const int wm = wave & 1;            // M half of tile
  const int wn = wave >> 1;           // N half

  f32x4 acc[4][4];
#pragma unroll
  for (int i = 0; i < 4; ++i)
#pragma unroll
    for (int j = 0; j < 4; ++j) acc[i][j] = f32x4{0.f, 0.f, 0.f, 0.f};

  for (int k0 = 0; k0 < 256; k0 += 64) {
    __syncthreads();
    // ---- stage A tile: 128 rows x 64 k (bf16) = 16 KB, 4 calls/wave
#pragma unroll
    for (int j = 0; j < 4; ++j) {
      int s = (wave * 4 + j) * 64 + lane;
      int r = s >> 3, cp = s & 7;
      int c = cp ^ (r & 7);
      int grow = rowBase + r;
      grow = grow < kN ? grow : kN - 1;   // clamp (garbage rows masked at store)
      const char* gp = (const char*)Ah + (size_t)grow * 512 + k0 * 2 + c * 16;
      load_lds16(gp, (char*)smemA + (wave * 4 + j) * 1024);
    }
    // ---- stage B tile: 128 n-rows x 64 k = 16 KB
#pragma unroll
    for (int j = 0; j < 4; ++j) {
      int s = (wave * 4 + j) * 64 + lane;
      int r = s >> 3, cp = s & 7;
      int c = cp ^ (r & 7);
      const char* gp = (const char*)Bt + (size_t)(colBase + r) * 512 + k0 * 2 + c * 16;
      load_lds16(gp, (char*)smemB + (wave * 4 + j) * 1024);
    }
    __syncthreads();

    const int rq = lane & 15, qd = lane >> 4;
#pragma unroll
    for (int ks = 0; ks < 2; ++ks) {
      bf16x8 af[4], bfr[4];
#pragma unroll
      for (int mi = 0; mi < 4; ++mi) {
        int r = wm * 64 + mi * 16 + rq;
        int c = (ks * 4 + qd) ^ (r & 7);
        af[mi] = *(const bf16x8*)&smemA[r * 64 + c * 8];
      }
#pragma unroll
      for (int nj = 0; nj < 4; ++nj) {
        int r = wn * 64 + nj * 16 + rq;
        int c = (ks * 4 + qd) ^ (r & 7);
        bfr[nj] = *(const bf16x8*)&smemB[r * 64 + c * 8];
      }
#pragma unroll
      for (int mi = 0; mi < 4; ++mi)
#pragma unroll
        for (int nj = 0; nj < 4; ++nj)
          acc[mi][nj] = __builtin_amdgcn_mfma_f32_16x16x32_bf16(
              af[mi], bfr[nj], acc[mi][nj], 0, 0, 0);
    }
  }

  // ---- epilogue: stage bf16 C tile in LDS, then coalesced stores.
  // C frag layout: row=(lane>>4)*4+reg, col=lane&15 (verified m89/m91).
  __syncthreads();   // tiles no longer needed; reuse as smemC
#pragma unroll
  for (int nj = 0; nj < 4; ++nj) {
    const int cl = wn * 64 + nj * 16 + (lane & 15);
    const float bb = biasP[colBase + cl];
#pragma unroll
    for (int mi = 0; mi < 4; ++mi) {
      const int rl = wm * 64 + mi * 16 + (lane >> 4) * 4;
#pragma unroll
      for (int reg = 0; reg < 4; ++reg) {
        smemC[(rl + reg) * 136 + cl] = (short)f2bu(acc[mi][nj][reg] + bb);
      }
    }
  }
  __syncthreads();

  const int g = colBase >> 8;   // block-uniform: 0=q 1=k 2=v
#pragma unroll
  for (int it = 0; it < 8; ++it) {
    const int r   = it * 16 + (tid >> 4);      // 0..127
    const int c16 = tid & 15;                  // 16B chunk within row
    const int row = rowBase + r;
    if (row < kN) {
      bf16x8 vls = *(const bf16x8*)&smemC[r * 136 + c16 * 8];
      const int cc = (colBase & 255) + c16 * 8;
      __hip_bfloat16* dst =
          (g == 0) ? (qb + (size_t)row * 256 + cc)
                   : (kvb + (size_t)row * 512 + (g == 2 ? 256 : 0) + cc);
      *(bf16x8*)dst = vls;
    }
  }
}

// ---------------------------------------------------------------------------
// Fused SDDMM + segment softmax + SpMM (v4).
//
// Structure = v2 (one row per wave, non-persistent) with:
//   - 128-thread blocks (2 waves): halves straggler slot-holding from
//     degree variance, 25000 independently-retiring blocks.
//   - packed (col,val) int2 loads: one dwordx2 per refill (was 2 loads).
//   - f32x2 packed math (v_pk_fma_f32): dot + accumulate at 2 ch/instr.
//   - col/val 16 edges ahead (ping-pong banks), k/v 8 edges ahead,
//     DPP quad reduction, log2(e) folded into q (p = exp2(s)).
// ---------------------------------------------------------------------------
__global__ __launch_bounds__(128, 7) void edge_attn_kernel(
    const __hip_bfloat16* __restrict__ qb, const __hip_bfloat16* __restrict__ kvb,
    const int* __restrict__ row_ptr, const i32x2* __restrict__ cvp,
    float* __restrict__ out) {
  const int wave = threadIdx.x >> 6;
  const int lane = threadIdx.x & 63;
  const int half = lane >> 5;        // which edge of the pair
  const int sl   = lane & 31;        // channel-group lane (8 ch each)
  const int row = blockIdx.x * 2 + wave;
  if (row >= kN) return;

  const int e0 = row_ptr[row];
  const int e1 = row_ptr[row + 1];

  // q channels sl*8 .. sl*8+7, pre-scaled by log2(e) so p = exp2(s)
  const us8 qu = *(const us8*)(qb + (size_t)row * 256 + sl * 8);
  f32x2 qf2[4];
#pragma unroll
  for (int j = 0; j < 4; ++j)
    qf2[j] = f32x2{b2f(qu[2 * j]) * 1.4426950408889634f,
                   b2f(qu[2 * j + 1]) * 1.4426950408889634f};

  float denom = 0.f;
  f32x2 acc2[4];
#pragma unroll
  for (int j = 0; j < 4; ++j) acc2[j] = f32x2{0.f, 0.f};

  if (e0 < e1) {
    const char* kvbL = (const char*)kvb + sl * 16;
    const int elast = e1 - 1;

    u32x4 kS[4], vS[4];        // k/v data for the CURRENT group's 8 edges
    float wS[4];               // val for the current group's 8 edges
    i32x2 cvA[4], cvB[4];      // (col,val) for groups +1 / +2 (ping-pong)

    // ---- warmup ----
    i32x2 c0[4];
#pragma unroll
    for (int j = 0; j < 4; ++j) {        // group 0 cols
      const int ea = min(e0 + 2 * j + half, elast);
      c0[j] = cvp[ea];
    }
#pragma unroll
    for (int j = 0; j < 4; ++j) {        // group 1 cols
      const int eb = min(e0 + 8 + 2 * j + half, elast);
      cvA[j] = cvp[eb];
    }
#pragma unroll
    for (int j = 0; j < 4; ++j) {        // group 2 cols (in flight thru group 0)
      const int ec = min(e0 + 16 + 2 * j + half, elast);
      cvB[j] = cvp[ec];
    }
#pragma unroll
    for (int j = 0; j < 4; ++j) {        // group 0 k/v gathers
      const size_t off = (size_t)c0[j][0] * 1024;
      kS[j] = *(const u32x4*)(kvbL + off);
      vS[j] = *(const u32x4*)(kvbL + off + 512);
      wS[j] = __int_as_float(c0[j][1]);
    }

    // GROUP(EB, CB): consumes edges [EB, EB+8); refills k/v for [EB+8, EB+16)
    // from bank CB (resident); loads (col,val) for [EB+24, EB+32) back into CB.
#define ATTN_GROUP(EB, CB)                                                \
    _Pragma("unroll")                                                     \
    for (int j = 0; j < 4; ++j) {                                         \
      const u32x4 kc = kS[j], vc = vS[j];                                 \
      const float wc = wS[j];                                             \
      {                                                                   \
        const size_t off = (size_t)CB[j][0] * 1024;                       \
        kS[j] = *(const u32x4*)(kvbL + off);                              \
        vS[j] = *(const u32x4*)(kvbL + off + 512);                        \
        wS[j] = __int_as_float(CB[j][1]);                                 \
      }                                                                   \
      {                                                                   \
        const int en = min((EB) + 24 + 2 * j + half, elast);              \
        CB[j] = cvp[en];                                                  \
      }                                                                   \
      f32x2 s2 = qf2[0] * bf2up(kc[0]);                                   \
      s2 += qf2[1] * bf2up(kc[1]);                                        \
      s2 += qf2[2] * bf2up(kc[2]);                                        \
      s2 += qf2[3] * bf2up(kc[3]);                                        \
      float s = s2[0] + s2[1];                                            \
      s = quad_add_xor1(s);                                               \
      s = quad_add_xor2(s);        /* 4-lane head group reduced */        \
      s *= wc;                                                            \
      float p = exp2f(s);                                                 \
      p = (((EB) + 2 * j + half) < e1) ? p : 0.f;                         \
      denom += p;                                                         \
      const f32x2 p2 = {p, p};                                            \
      acc2[0] += p2 * bf2up(vc[0]);                                       \
      acc2[1] += p2 * bf2up(vc[1]);                                       \
      acc2[2] += p2 * bf2up(vc[2]);                                       \
      acc2[3] += p2 * bf2up(vc[3]);                                       \
    }

    for (int e = e0; e < e1; e += 16) {
      ATTN_GROUP(e, cvA);
      ATTN_GROUP(e + 8, cvB);
    }
#undef ATTN_GROUP
  }

  // combine the two halves
  float accs[8];
#pragma unroll
  for (int j = 0; j < 8; ++j) {
    float a = (j & 1) ? acc2[j >> 1][1] : acc2[j >> 1][0];
    accs[j] = a + __shfl_xor(a, 32);
  }
  denom += __shfl_xor(denom, 32);

  const float inv = (denom > 0.f) ? (1.0f / denom) : 0.f;
  // lane's channels cc = sl*8 + j live in head h = sl>>2, dim d=(sl&3)*8+j.
  // This lane writes j = half*4 .. half*4+3; ref channel c = d*8 + h.
  const int h = sl >> 2;
  const int dbase = (sl & 3) * 8 + half * 4;
  float* o = out + (size_t)row * 256 + h;
#pragma unroll
  for (int jj = 0; jj < 4; ++jj)
    o[(dbase + jj) * 8] = accs[half * 4 + jj] * inv;
}

// ---------------------------------------------------------------------------
extern "C" void kernel_launch(void* const* d_in, const int* in_sizes, int n_in,
                              void* d_out, int out_size, void* d_ws, size_t ws_size,
                              hipStream_t stream) {
  const float* h   = (const float*)d_in[0];
  const float* val = (const float*)d_in[1];
  const float* Wq  = (const float*)d_in[2];
  const float* bq  = (const float*)d_in[3];
  const float* Wk  = (const float*)d_in[4];
  const float* bk  = (const float*)d_in[5];
  const float* Wv  = (const float*)d_in[6];
  const float* bv  = (const float*)d_in[7];
  const int* edge_rows = (const int*)d_in[8];
  const int* col_ind   = (const int*)d_in[9];
  float* out = (float*)d_out;

  char* ws = (char*)d_ws;
  __hip_bfloat16* Ah  = (__hip_bfloat16*)ws;                 ws += (size_t)kN * 256 * 2;
  __hip_bfloat16* Bt  = (__hip_bfloat16*)ws;                 ws += (size_t)768 * 256 * 2;
  float*          biasP = (float*)ws;                        ws += 768 * 4;
  __hip_bfloat16* qb  = (__hip_bfloat16*)ws;                 ws += (size_t)kN * 256 * 2;
  __hip_bfloat16* kvb = (__hip_bfloat16*)ws;                 ws += (size_t)kN * 512 * 2;
  int* row_ptr = (int*)ws;                                   ws += ((size_t)(kN + 1) * 4 + 127) & ~127ull;
  i32x2* cv = (i32x2*)ws;

  split_h_kernel<<<kN / 8, 256, 0, stream>>>(h, Ah);          // 8 elems/thread
  build_bt_kernel<<<768, 256, 0, stream>>>(Wq, bq, Wk, bk, Wv, bv, Bt, biasP);
  prep_kernel<<<196 + 782, 256, 0, stream>>>(edge_rows, row_ptr, col_ind, val, cv);

  // 391 M-tiles padded to 49 groups of 8; 6 N-tiles; 8 XCD slots
  gemm_qkv_kernel<<<8 * 6 * 49, 256, 0, stream>>>(Ah, Bt, biasP, qb, kvb);

  edge_attn_kernel<<<(kN + 1) / 2, 128, 0, stream>>>(qb, kvb, row_ptr, cv, out);
}

// Round 6
// 273.703 us; speedup vs baseline: 1.6533x; 1.6533x over previous
//
#include <hip/hip_runtime.h>
#include <hip/hip_bf16.h>
#include <math.h>

static constexpr int kN   = 50000;   // nodes
static constexpr int kE   = 800000;  // edges
static constexpr int kHID = 256;
static constexpr int kHD  = 32;

typedef short bf16x8 __attribute__((ext_vector_type(8)));
typedef float f32x4  __attribute__((ext_vector_type(4)));
typedef float f32x2  __attribute__((ext_vector_type(2)));
typedef unsigned short us8 __attribute__((ext_vector_type(8)));
typedef unsigned int u32x4 __attribute__((ext_vector_type(4)));
typedef int i32x2 __attribute__((ext_vector_type(2)));
typedef int i32x4 __attribute__((ext_vector_type(4)));

__device__ __forceinline__ float b2f(unsigned short u) {
  union { unsigned v; float f; } c; c.v = ((unsigned)u) << 16; return c.f;
}

__device__ __forceinline__ unsigned short f2bu(float f) {
  __hip_bfloat16 b = __float2bfloat16(f);
  union { __hip_bfloat16 b; unsigned short u; } c; c.b = b; return c.u;
}

// unpack u32 holding 2 bf16 (channels 2j, 2j+1) into f32x2
__device__ __forceinline__ f32x2 bf2up(unsigned u) {
  union { unsigned v; float f; } lo, hi;
  lo.v = u << 16; hi.v = u & 0xffff0000u;
  return f32x2{lo.f, hi.f};
}

// quad-local butterfly add via DPP (no LDS round-trip).
__device__ __forceinline__ float quad_add_xor1(float s) {
  union { float f; int i; } a, b;
  a.f = s;
  b.i = __builtin_amdgcn_mov_dpp(a.i, 0xB1, 0xF, 0xF, true);  // quad_perm [1,0,3,2]
  return s + b.f;
}
__device__ __forceinline__ float quad_add_xor2(float s) {
  union { float f; int i; } a, b;
  a.f = s;
  b.i = __builtin_amdgcn_mov_dpp(a.i, 0x4E, 0xF, 0xF, true);  // quad_perm [2,3,0,1]
  return s + b.f;
}

// global -> LDS async copy, 16 B per lane; LDS dest = uniform base + lane*16
__device__ __forceinline__ void load_lds16(const void* g, void* l) {
  __builtin_amdgcn_global_load_lds(
      (const __attribute__((address_space(1))) unsigned int*)(unsigned long long)(uintptr_t)g,
      (__attribute__((address_space(3))) unsigned int*)(unsigned int)(uintptr_t)l,
      16, 0, 0);
}

// ---------------------------------------------------------------------------
// h -> bf16, 8 elements/thread (vectorized loads + 16B stores)
// ---------------------------------------------------------------------------
__global__ void split_h_kernel(const float* __restrict__ h,
                               __hip_bfloat16* __restrict__ Ah) {
  int idx = blockIdx.x * 256 + threadIdx.x;   // N*256/8 threads exactly
  const f32x4* hp = (const f32x4*)(h + (size_t)idx * 8);
  f32x4 a = hp[0], b = hp[1];
  us8 o;
  o[0] = f2bu(a[0]); o[1] = f2bu(a[1]); o[2] = f2bu(a[2]); o[3] = f2bu(a[3]);
  o[4] = f2bu(b[0]); o[5] = f2bu(b[1]); o[6] = f2bu(b[2]); o[7] = f2bu(b[3]);
  *(us8*)(Ah + (size_t)idx * 8) = o;
}

// ---------------------------------------------------------------------------
// Build Bt[768][256] bf16 (B transposed, n-major) + biasP[768] fp32.
// n: 0-255 q, 256-511 k, 512-767 v; channel permuted cc=h*32+d <- c=d*8+h,
// softmax scaling folded into the q group (weights AND bias).
// ---------------------------------------------------------------------------
__global__ void build_bt_kernel(const float* __restrict__ Wq, const float* __restrict__ bq,
                                const float* __restrict__ Wk, const float* __restrict__ bk,
                                const float* __restrict__ Wv, const float* __restrict__ bv,
                                __hip_bfloat16* __restrict__ Bt, float* __restrict__ biasP) {
  const int n  = blockIdx.x;          // 0..767
  const int kk = threadIdx.x;         // 0..255
  const int g  = n >> 8;
  const int cc = n & 255;
  const int c  = ((cc & 31) << 3) + (cc >> 5);     // ref channel d*8+h
  const float scale = (g == 0) ? 0.17677669529663689f : 1.0f;  // HD^-0.5
  const float* W = (g == 0) ? Wq : ((g == 1) ? Wk : Wv);
  Bt[n * 256 + kk] = __float2bfloat16(W[kk * 256 + c] * scale);
  if (kk == 0) {
    const float* b = (g == 0) ? bq : ((g == 1) ? bk : bv);
    biasP[n] = b[c] * scale;
  }
}

// ---------------------------------------------------------------------------
// Fused prep: blocks 0..195 build row_ptr (lower_bound over sorted edge_rows);
// blocks 196.. pack (col_ind, val) into interleaved int2 cv[] (one dwordx2
// per edge in the attention loop instead of two dword loads).
// ---------------------------------------------------------------------------
__global__ void prep_kernel(const int* __restrict__ er, int* __restrict__ rp,
                            const int* __restrict__ ci, const float* __restrict__ vl,
                            i32x2* __restrict__ cv) {
  const int b = blockIdx.x;
  if (b < 196) {
    int i = b * 256 + threadIdx.x;
    if (i > kN) return;
    int lo = 0, hi = kE;
    while (lo < hi) {
      int mid = (lo + hi) >> 1;
      if (er[mid] < i) lo = mid + 1; else hi = mid;
    }
    rp[i] = lo;
  } else {
    const int e4 = ((b - 196) * 256 + threadIdx.x) * 4;
    if (e4 < kE) {
      i32x4 c = *(const i32x4*)(ci + e4);
      f32x4 w = *(const f32x4*)(vl + e4);
      i32x4 o0 = {c[0], __float_as_int(w[0]), c[1], __float_as_int(w[1])};
      i32x4 o1 = {c[2], __float_as_int(w[2]), c[3], __float_as_int(w[3])};
      *(i32x4*)(cv + e4)     = o0;
      *(i32x4*)(cv + e4 + 2) = o1;
    }
  }
}

// ---------------------------------------------------------------------------
// Fused MFMA GEMM: C[M=50000][768] = A[M][256] * Bt[768][256]^T + bias.
// 128x128 tile, BK=64, 256 threads (4 waves 2x2), global_load_lds staging,
// XOR-swizzled LDS (conflict-free). 1-D grid with XCD-aware decode: all 6
// N-tiles sharing an A-panel land on the SAME XCD consecutively (A in L2).
// Epilogue: C tile staged bf16 in LDS (padded), stored as coalesced 16B chunks.
// ---------------------------------------------------------------------------
__global__ __launch_bounds__(256) void gemm_qkv_kernel(
    const __hip_bfloat16* __restrict__ Ah,
    const __hip_bfloat16* __restrict__ Bt, const float* __restrict__ biasP,
    __hip_bfloat16* __restrict__ qb, __hip_bfloat16* __restrict__ kvb) {
  __shared__ __align__(16) char smemRaw[34816];   // max(32 KB tiles, 128*136*2 C)
  short* smemA = (short*)smemRaw;                 // [128][64] 16B-chunk swizzled
  short* smemB = (short*)(smemRaw + 16384);
  short* smemC = (short*)smemRaw;                 // [128][136] padded C tile

  // XCD-aware decode: L = xcd + 8*(n + 6*mg), m-tile = mg*8 + xcd
  const int L   = blockIdx.x;
  const int xcd = L & 7;
  const int t   = L >> 3;
  const int nt  = t % 6;
  const int mg  = t / 6;
  const int mt  = mg * 8 + xcd;
  if (mt >= 391) return;
  const int colBase = nt * 128;
  const int rowBase = mt * 128;

  const int tid  = threadIdx.x;
  const int wave = tid >> 6;
  const int lane = tid & 63;
  const int wm = wave & 1;            // M half of tile
  const int wn = wave >> 1;           // N half

  f32x4 acc[4][4];
#pragma unroll
  for (int i = 0; i < 4; ++i)
#pragma unroll
    for (int j = 0; j < 4; ++j) acc[i][j] = f32x4{0.f, 0.f, 0.f, 0.f};

  for (int k0 = 0; k0 < 256; k0 += 64) {
    __syncthreads();
    // ---- stage A tile: 128 rows x 64 k (bf16) = 16 KB, 4 calls/wave
#pragma unroll
    for (int j = 0; j < 4; ++j) {
      int s = (wave * 4 + j) * 64 + lane;
      int r = s >> 3, cp = s & 7;
      int c = cp ^ (r & 7);
      int grow = rowBase + r;
      grow = grow < kN ? grow : kN - 1;   // clamp (garbage rows masked at store)
      const char* gp = (const char*)Ah + (size_t)grow * 512 + k0 * 2 + c * 16;
      load_lds16(gp, (char*)smemA + (wave * 4 + j) * 1024);
    }
    // ---- stage B tile: 128 n-rows x 64 k = 16 KB
#pragma unroll
    for (int j = 0; j < 4; ++j) {
      int s = (wave * 4 + j) * 64 + lane;
      int r = s >> 3, cp = s & 7;
      int c = cp ^ (r & 7);
      const char* gp = (const char*)Bt + (size_t)(colBase + r) * 512 + k0 * 2 + c * 16;
      load_lds16(gp, (char*)smemB + (wave * 4 + j) * 1024);
    }
    __syncthreads();

    const int rq = lane & 15, qd = lane >> 4;
#pragma unroll
    for (int ks = 0; ks < 2; ++ks) {
      bf16x8 af[4], bfr[4];
#pragma unroll
      for (int mi = 0; mi < 4; ++mi) {
        int r = wm * 64 + mi * 16 + rq;
        int c = (ks * 4 + qd) ^ (r & 7);
        af[mi] = *(const bf16x8*)&smemA[r * 64 + c * 8];
      }
#pragma unroll
      for (int nj = 0; nj < 4; ++nj) {
        int r = wn * 64 + nj * 16 + rq;
        int c = (ks * 4 + qd) ^ (r & 7);
        bfr[nj] = *(const bf16x8*)&smemB[r * 64 + c * 8];
      }
#pragma unroll
      for (int mi = 0; mi < 4; ++mi)
#pragma unroll
        for (int nj = 0; nj < 4; ++nj)
          acc[mi][nj] = __builtin_amdgcn_mfma_f32_16x16x32_bf16(
              af[mi], bfr[nj], acc[mi][nj], 0, 0, 0);
    }
  }

  // ---- epilogue: stage bf16 C tile in LDS, then coalesced stores.
  // C frag layout: row=(lane>>4)*4+reg, col=lane&15 (verified m89/m91).
  __syncthreads();   // tiles no longer needed; reuse as smemC
#pragma unroll
  for (int nj = 0; nj < 4; ++nj) {
    const int cl = wn * 64 + nj * 16 + (lane & 15);
    const float bb = biasP[colBase + cl];
#pragma unroll
    for (int mi = 0; mi < 4; ++mi) {
      const int rl = wm * 64 + mi * 16 + (lane >> 4) * 4;
#pragma unroll
      for (int reg = 0; reg < 4; ++reg) {
        smemC[(rl + reg) * 136 + cl] = (short)f2bu(acc[mi][nj][reg] + bb);
      }
    }
  }
  __syncthreads();

  const int g = colBase >> 8;   // block-uniform: 0=q 1=k 2=v
#pragma unroll
  for (int it = 0; it < 8; ++it) {
    const int r   = it * 16 + (tid >> 4);      // 0..127
    const int c16 = tid & 15;                  // 16B chunk within row
    const int row = rowBase + r;
    if (row < kN) {
      bf16x8 vls = *(const bf16x8*)&smemC[r * 136 + c16 * 8];
      const int cc = (colBase & 255) + c16 * 8;
      __hip_bfloat16* dst =
          (g == 0) ? (qb + (size_t)row * 256 + cc)
                   : (kvb + (size_t)row * 512 + (g == 2 ? 256 : 0) + cc);
      *(bf16x8*)dst = vls;
    }
  }
}

// ---------------------------------------------------------------------------
// Fused SDDMM + segment softmax + SpMM (v5 = v4 with the spill fixed).
//
// v4's __launch_bounds__(128, 7) forced VGPR=36 -> pipeline arrays spilled
// to scratch (WRITE_SIZE 50->594 MB, dur 119->290 us). v5 drops the
// min-waves clamp; compiler allocates what the pipeline needs (~70-90).
//
// Structure = v2 (one row per wave, non-persistent) with:
//   - 128-thread blocks (2 waves): less straggler slot-holding from
//     degree variance, 25000 independently-retiring blocks.
//   - packed (col,val) int2 loads: one dwordx2 per refill (was 2 loads).
//   - f32x2 packed math (v_pk_fma_f32): dot + accumulate at 2 ch/instr.
//   - col/val 16 edges ahead (ping-pong banks), k/v 8 edges ahead,
//     DPP quad reduction, log2(e) folded into q (p = exp2(s)).
// ---------------------------------------------------------------------------
__global__ __launch_bounds__(128) void edge_attn_kernel(
    const __hip_bfloat16* __restrict__ qb, const __hip_bfloat16* __restrict__ kvb,
    const int* __restrict__ row_ptr, const i32x2* __restrict__ cvp,
    float* __restrict__ out) {
  const int wave = threadIdx.x >> 6;
  const int lane = threadIdx.x & 63;
  const int half = lane >> 5;        // which edge of the pair
  const int sl   = lane & 31;        // channel-group lane (8 ch each)
  const int row = blockIdx.x * 2 + wave;
  if (row >= kN) return;

  const int e0 = row_ptr[row];
  const int e1 = row_ptr[row + 1];

  // q channels sl*8 .. sl*8+7, pre-scaled by log2(e) so p = exp2(s)
  const us8 qu = *(const us8*)(qb + (size_t)row * 256 + sl * 8);
  f32x2 qf2[4];
#pragma unroll
  for (int j = 0; j < 4; ++j)
    qf2[j] = f32x2{b2f(qu[2 * j]) * 1.4426950408889634f,
                   b2f(qu[2 * j + 1]) * 1.4426950408889634f};

  float denom = 0.f;
  f32x2 acc2[4];
#pragma unroll
  for (int j = 0; j < 4; ++j) acc2[j] = f32x2{0.f, 0.f};

  if (e0 < e1) {
    const char* kvbL = (const char*)kvb + sl * 16;
    const int elast = e1 - 1;

    u32x4 kS[4], vS[4];        // k/v data for the CURRENT group's 8 edges
    float wS[4];               // val for the current group's 8 edges
    i32x2 cvA[4], cvB[4];      // (col,val) for groups +1 / +2 (ping-pong)

    // ---- warmup ----
    i32x2 c0[4];
#pragma unroll
    for (int j = 0; j < 4; ++j) {        // group 0 cols
      const int ea = min(e0 + 2 * j + half, elast);
      c0[j] = cvp[ea];
    }
#pragma unroll
    for (int j = 0; j < 4; ++j) {        // group 1 cols
      const int eb = min(e0 + 8 + 2 * j + half, elast);
      cvA[j] = cvp[eb];
    }
#pragma unroll
    for (int j = 0; j < 4; ++j) {        // group 2 cols (in flight thru group 0)
      const int ec = min(e0 + 16 + 2 * j + half, elast);
      cvB[j] = cvp[ec];
    }
#pragma unroll
    for (int j = 0; j < 4; ++j) {        // group 0 k/v gathers
      const size_t off = (size_t)c0[j][0] * 1024;
      kS[j] = *(const u32x4*)(kvbL + off);
      vS[j] = *(const u32x4*)(kvbL + off + 512);
      wS[j] = __int_as_float(c0[j][1]);
    }

    // GROUP(EB, CB): consumes edges [EB, EB+8); refills k/v for [EB+8, EB+16)
    // from bank CB (resident); loads (col,val) for [EB+24, EB+32) back into CB.
#define ATTN_GROUP(EB, CB)                                                \
    _Pragma("unroll")                                                     \
    for (int j = 0; j < 4; ++j) {                                         \
      const u32x4 kc = kS[j], vc = vS[j];                                 \
      const float wc = wS[j];                                             \
      {                                                                   \
        const size_t off = (size_t)CB[j][0] * 1024;                       \
        kS[j] = *(const u32x4*)(kvbL + off);                              \
        vS[j] = *(const u32x4*)(kvbL + off + 512);                        \
        wS[j] = __int_as_float(CB[j][1]);                                 \
      }                                                                   \
      {                                                                   \
        const int en = min((EB) + 24 + 2 * j + half, elast);              \
        CB[j] = cvp[en];                                                  \
      }                                                                   \
      f32x2 s2 = qf2[0] * bf2up(kc[0]);                                   \
      s2 += qf2[1] * bf2up(kc[1]);                                        \
      s2 += qf2[2] * bf2up(kc[2]);                                        \
      s2 += qf2[3] * bf2up(kc[3]);                                        \
      float s = s2[0] + s2[1];                                            \
      s = quad_add_xor1(s);                                               \
      s = quad_add_xor2(s);        /* 4-lane head group reduced */        \
      s *= wc;                                                            \
      float p = exp2f(s);                                                 \
      p = (((EB) + 2 * j + half) < e1) ? p : 0.f;                         \
      denom += p;                                                         \
      const f32x2 p2 = {p, p};                                            \
      acc2[0] += p2 * bf2up(vc[0]);                                       \
      acc2[1] += p2 * bf2up(vc[1]);                                       \
      acc2[2] += p2 * bf2up(vc[2]);                                       \
      acc2[3] += p2 * bf2up(vc[3]);                                       \
    }

    for (int e = e0; e < e1; e += 16) {
      ATTN_GROUP(e, cvA);
      ATTN_GROUP(e + 8, cvB);
    }
#undef ATTN_GROUP
  }

  // combine the two halves
  float accs[8];
#pragma unroll
  for (int j = 0; j < 8; ++j) {
    float a = (j & 1) ? acc2[j >> 1][1] : acc2[j >> 1][0];
    accs[j] = a + __shfl_xor(a, 32);
  }
  denom += __shfl_xor(denom, 32);

  const float inv = (denom > 0.f) ? (1.0f / denom) : 0.f;
  // lane's channels cc = sl*8 + j live in head h = sl>>2, dim d=(sl&3)*8+j.
  // This lane writes j = half*4 .. half*4+3; ref channel c = d*8 + h.
  const int h = sl >> 2;
  const int dbase = (sl & 3) * 8 + half * 4;
  float* o = out + (size_t)row * 256 + h;
#pragma unroll
  for (int jj = 0; jj < 4; ++jj)
    o[(dbase + jj) * 8] = accs[half * 4 + jj] * inv;
}

// ---------------------------------------------------------------------------
extern "C" void kernel_launch(void* const* d_in, const int* in_sizes, int n_in,
                              void* d_out, int out_size, void* d_ws, size_t ws_size,
                              hipStream_t stream) {
  const float* h   = (const float*)d_in[0];
  const float* val = (const float*)d_in[1];
  const float* Wq  = (const float*)d_in[2];
  const float* bq  = (const float*)d_in[3];
  const float* Wk  = (const float*)d_in[4];
  const float* bk  = (const float*)d_in[5];
  const float* Wv  = (const float*)d_in[6];
  const float* bv  = (const float*)d_in[7];
  const int* edge_rows = (const int*)d_in[8];
  const int* col_ind   = (const int*)d_in[9];
  float* out = (float*)d_out;

  char* ws = (char*)d_ws;
  __hip_bfloat16* Ah  = (__hip_bfloat16*)ws;                 ws += (size_t)kN * 256 * 2;
  __hip_bfloat16* Bt  = (__hip_bfloat16*)ws;                 ws += (size_t)768 * 256 * 2;
  float*          biasP = (float*)ws;                        ws += 768 * 4;
  __hip_bfloat16* qb  = (__hip_bfloat16*)ws;                 ws += (size_t)kN * 256 * 2;
  __hip_bfloat16* kvb = (__hip_bfloat16*)ws;                 ws += (size_t)kN * 512 * 2;
  int* row_ptr = (int*)ws;                                   ws += ((size_t)(kN + 1) * 4 + 127) & ~127ull;
  i32x2* cv = (i32x2*)ws;

  split_h_kernel<<<kN / 8, 256, 0, stream>>>(h, Ah);          // 8 elems/thread
  build_bt_kernel<<<768, 256, 0, stream>>>(Wq, bq, Wk, bk, Wv, bv, Bt, biasP);
  prep_kernel<<<196 + 782, 256, 0, stream>>>(edge_rows, row_ptr, col_ind, val, cv);

  // 391 M-tiles padded to 49 groups of 8; 6 N-tiles; 8 XCD slots
  gemm_qkv_kernel<<<8 * 6 * 49, 256, 0, stream>>>(Ah, Bt, biasP, qb, kvb);

  edge_attn_kernel<<<(kN + 1) / 2, 128, 0, stream>>>(qb, kvb, row_ptr, cv, out);
}

// Round 7
// 270.289 us; speedup vs baseline: 1.6742x; 1.0126x over previous
//
#include <hip/hip_runtime.h>
#include <hip/hip_bf16.h>
#include <math.h>

static constexpr int kN   = 50000;   // nodes
static constexpr int kE   = 800000;  // edges
static constexpr int kHID = 256;
static constexpr int kHD  = 32;

typedef short bf16x8 __attribute__((ext_vector_type(8)));
typedef float f32x4  __attribute__((ext_vector_type(4)));
typedef float f32x2  __attribute__((ext_vector_type(2)));
typedef unsigned short us8 __attribute__((ext_vector_type(8)));
typedef unsigned int u32x4 __attribute__((ext_vector_type(4)));
typedef int i32x2 __attribute__((ext_vector_type(2)));
typedef int i32x4 __attribute__((ext_vector_type(4)));

__device__ __forceinline__ float b2f(unsigned short u) {
  union { unsigned v; float f; } c; c.v = ((unsigned)u) << 16; return c.f;
}

__device__ __forceinline__ unsigned short f2bu(float f) {
  __hip_bfloat16 b = __float2bfloat16(f);
  union { __hip_bfloat16 b; unsigned short u; } c; c.b = b; return c.u;
}

// unpack u32 holding 2 bf16 (channels 2j, 2j+1) into f32x2
__device__ __forceinline__ f32x2 bf2up(unsigned u) {
  union { unsigned v; float f; } lo, hi;
  lo.v = u << 16; hi.v = u & 0xffff0000u;
  return f32x2{lo.f, hi.f};
}

// quad-local butterfly add via DPP (no LDS round-trip).
__device__ __forceinline__ float quad_add_xor1(float s) {
  union { float f; int i; } a, b;
  a.f = s;
  b.i = __builtin_amdgcn_mov_dpp(a.i, 0xB1, 0xF, 0xF, true);  // quad_perm [1,0,3,2]
  return s + b.f;
}
__device__ __forceinline__ float quad_add_xor2(float s) {
  union { float f; int i; } a, b;
  a.f = s;
  b.i = __builtin_amdgcn_mov_dpp(a.i, 0x4E, 0xF, 0xF, true);  // quad_perm [2,3,0,1]
  return s + b.f;
}

// global -> LDS async copy, 16 B per lane; LDS dest = uniform base + lane*16
__device__ __forceinline__ void load_lds16(const void* g, void* l) {
  __builtin_amdgcn_global_load_lds(
      (const __attribute__((address_space(1))) unsigned int*)(unsigned long long)(uintptr_t)g,
      (__attribute__((address_space(3))) unsigned int*)(unsigned int)(uintptr_t)l,
      16, 0, 0);
}

// ---------------------------------------------------------------------------
// h -> bf16, 8 elements/thread (vectorized loads + 16B stores)
// ---------------------------------------------------------------------------
__global__ void split_h_kernel(const float* __restrict__ h,
                               __hip_bfloat16* __restrict__ Ah) {
  int idx = blockIdx.x * 256 + threadIdx.x;   // N*256/8 threads exactly
  const f32x4* hp = (const f32x4*)(h + (size_t)idx * 8);
  f32x4 a = hp[0], b = hp[1];
  us8 o;
  o[0] = f2bu(a[0]); o[1] = f2bu(a[1]); o[2] = f2bu(a[2]); o[3] = f2bu(a[3]);
  o[4] = f2bu(b[0]); o[5] = f2bu(b[1]); o[6] = f2bu(b[2]); o[7] = f2bu(b[3]);
  *(us8*)(Ah + (size_t)idx * 8) = o;
}

// ---------------------------------------------------------------------------
// Build Bt[768][256] bf16 (B transposed, n-major) + biasP[768] fp32.
// n: 0-255 q, 256-511 k, 512-767 v; channel permuted cc=h*32+d <- c=d*8+h,
// softmax scaling folded into the q group (weights AND bias).
// ---------------------------------------------------------------------------
__global__ void build_bt_kernel(const float* __restrict__ Wq, const float* __restrict__ bq,
                                const float* __restrict__ Wk, const float* __restrict__ bk,
                                const float* __restrict__ Wv, const float* __restrict__ bv,
                                __hip_bfloat16* __restrict__ Bt, float* __restrict__ biasP) {
  const int n  = blockIdx.x;          // 0..767
  const int kk = threadIdx.x;         // 0..255
  const int g  = n >> 8;
  const int cc = n & 255;
  const int c  = ((cc & 31) << 3) + (cc >> 5);     // ref channel d*8+h
  const float scale = (g == 0) ? 0.17677669529663689f : 1.0f;  // HD^-0.5
  const float* W = (g == 0) ? Wq : ((g == 1) ? Wk : Wv);
  Bt[n * 256 + kk] = __float2bfloat16(W[kk * 256 + c] * scale);
  if (kk == 0) {
    const float* b = (g == 0) ? bq : ((g == 1) ? bk : bv);
    biasP[n] = b[c] * scale;
  }
}

// ---------------------------------------------------------------------------
// Fused prep: blocks 0..195 build row_ptr (lower_bound over sorted edge_rows);
// blocks 196.. pack (col_ind, val) into interleaved int2 cv[] (one dwordx2
// per edge in the attention loop instead of two dword loads).
// ---------------------------------------------------------------------------
__global__ void prep_kernel(const int* __restrict__ er, int* __restrict__ rp,
                            const int* __restrict__ ci, const float* __restrict__ vl,
                            i32x2* __restrict__ cv) {
  const int b = blockIdx.x;
  if (b < 196) {
    int i = b * 256 + threadIdx.x;
    if (i > kN) return;
    int lo = 0, hi = kE;
    while (lo < hi) {
      int mid = (lo + hi) >> 1;
      if (er[mid] < i) lo = mid + 1; else hi = mid;
    }
    rp[i] = lo;
  } else {
    const int e4 = ((b - 196) * 256 + threadIdx.x) * 4;
    if (e4 < kE) {
      i32x4 c = *(const i32x4*)(ci + e4);
      f32x4 w = *(const f32x4*)(vl + e4);
      i32x4 o0 = {c[0], __float_as_int(w[0]), c[1], __float_as_int(w[1])};
      i32x4 o1 = {c[2], __float_as_int(w[2]), c[3], __float_as_int(w[3])};
      *(i32x4*)(cv + e4)     = o0;
      *(i32x4*)(cv + e4 + 2) = o1;
    }
  }
}

// ---------------------------------------------------------------------------
// Fused MFMA GEMM: C[M=50000][768] = A[M][256] * Bt[768][256]^T + bias.
// 128x128 tile, BK=64, 256 threads (4 waves 2x2), global_load_lds staging,
// XOR-swizzled LDS (conflict-free). 1-D grid with XCD-aware decode: all 6
// N-tiles sharing an A-panel land on the SAME XCD consecutively (A in L2).
// Epilogue: C tile staged bf16 in LDS (padded), stored as coalesced 16B chunks.
// ---------------------------------------------------------------------------
__global__ __launch_bounds__(256) void gemm_qkv_kernel(
    const __hip_bfloat16* __restrict__ Ah,
    const __hip_bfloat16* __restrict__ Bt, const float* __restrict__ biasP,
    __hip_bfloat16* __restrict__ qb, __hip_bfloat16* __restrict__ kvb) {
  __shared__ __align__(16) char smemRaw[34816];   // max(32 KB tiles, 128*136*2 C)
  short* smemA = (short*)smemRaw;                 // [128][64] 16B-chunk swizzled
  short* smemB = (short*)(smemRaw + 16384);
  short* smemC = (short*)smemRaw;                 // [128][136] padded C tile

  // XCD-aware decode: L = xcd + 8*(n + 6*mg), m-tile = mg*8 + xcd
  const int L   = blockIdx.x;
  const int xcd = L & 7;
  const int t   = L >> 3;
  const int nt  = t % 6;
  const int mg  = t / 6;
  const int mt  = mg * 8 + xcd;
  if (mt >= 391) return;
  const int colBase = nt * 128;
  const int rowBase = mt * 128;

  const int tid  = threadIdx.x;
  const int wave = tid >> 6;
  const int lane = tid & 63;
  const int wm = wave & 1;            // M half of tile
  const int wn = wave >> 1;           // N half

  f32x4 acc[4][4];
#pragma unroll
  for (int i = 0; i < 4; ++i)
#pragma unroll
    for (int j = 0; j < 4; ++j) acc[i][j] = f32x4{0.f, 0.f, 0.f, 0.f};

  for (int k0 = 0; k0 < 256; k0 += 64) {
    __syncthreads();
    // ---- stage A tile: 128 rows x 64 k (bf16) = 16 KB, 4 calls/wave
#pragma unroll
    for (int j = 0; j < 4; ++j) {
      int s = (wave * 4 + j) * 64 + lane;
      int r = s >> 3, cp = s & 7;
      int c = cp ^ (r & 7);
      int grow = rowBase + r;
      grow = grow < kN ? grow : kN - 1;   // clamp (garbage rows masked at store)
      const char* gp = (const char*)Ah + (size_t)grow * 512 + k0 * 2 + c * 16;
      load_lds16(gp, (char*)smemA + (wave * 4 + j) * 1024);
    }
    // ---- stage B tile: 128 n-rows x 64 k = 16 KB
#pragma unroll
    for (int j = 0; j < 4; ++j) {
      int s = (wave * 4 + j) * 64 + lane;
      int r = s >> 3, cp = s & 7;
      int c = cp ^ (r & 7);
      const char* gp = (const char*)Bt + (size_t)(colBase + r) * 512 + k0 * 2 + c * 16;
      load_lds16(gp, (char*)smemB + (wave * 4 + j) * 1024);
    }
    __syncthreads();

    const int rq = lane & 15, qd = lane >> 4;
#pragma unroll
    for (int ks = 0; ks < 2; ++ks) {
      bf16x8 af[4], bfr[4];
#pragma unroll
      for (int mi = 0; mi < 4; ++mi) {
        int r = wm * 64 + mi * 16 + rq;
        int c = (ks * 4 + qd) ^ (r & 7);
        af[mi] = *(const bf16x8*)&smemA[r * 64 + c * 8];
      }
#pragma unroll
      for (int nj = 0; nj < 4; ++nj) {
        int r = wn * 64 + nj * 16 + rq;
        int c = (ks * 4 + qd) ^ (r & 7);
        bfr[nj] = *(const bf16x8*)&smemB[r * 64 + c * 8];
      }
#pragma unroll
      for (int mi = 0; mi < 4; ++mi)
#pragma unroll
        for (int nj = 0; nj < 4; ++nj)
          acc[mi][nj] = __builtin_amdgcn_mfma_f32_16x16x32_bf16(
              af[mi], bfr[nj], acc[mi][nj], 0, 0, 0);
    }
  }

  // ---- epilogue: stage bf16 C tile in LDS, then coalesced stores.
  // C frag layout: row=(lane>>4)*4+reg, col=lane&15 (verified m89/m91).
  __syncthreads();   // tiles no longer needed; reuse as smemC
#pragma unroll
  for (int nj = 0; nj < 4; ++nj) {
    const int cl = wn * 64 + nj * 16 + (lane & 15);
    const float bb = biasP[colBase + cl];
#pragma unroll
    for (int mi = 0; mi < 4; ++mi) {
      const int rl = wm * 64 + mi * 16 + (lane >> 4) * 4;
#pragma unroll
      for (int reg = 0; reg < 4; ++reg) {
        smemC[(rl + reg) * 136 + cl] = (short)f2bu(acc[mi][nj][reg] + bb);
      }
    }
  }
  __syncthreads();

  const int g = colBase >> 8;   // block-uniform: 0=q 1=k 2=v
#pragma unroll
  for (int it = 0; it < 8; ++it) {
    const int r   = it * 16 + (tid >> 4);      // 0..127
    const int c16 = tid & 15;                  // 16B chunk within row
    const int row = rowBase + r;
    if (row < kN) {
      bf16x8 vls = *(const bf16x8*)&smemC[r * 136 + c16 * 8];
      const int cc = (colBase & 255) + c16 * 8;
      __hip_bfloat16* dst =
          (g == 0) ? (qb + (size_t)row * 256 + cc)
                   : (kvb + (size_t)row * 512 + (g == 2 ? 256 : 0) + cc);
      *(bf16x8*)dst = vls;
    }
  }
}

// ---------------------------------------------------------------------------
// Fused SDDMM + segment softmax + SpMM (v6).
//
// v6 = v5 with STRIDE-8 loop granularity: the loop-exit check moves BETWEEN
// the two unrolled ATTN_GROUPs (banks stay statically indexed). Work per row
// drops from ceil(deg/16)*16 to ceil(deg/8)*8 edge-slots: for deg~Bin(16,
// sd 4) that is E[slots] 23.2 -> 19.5 (-16% of edge work). Masked tail slots
// previously issued full (cache-hot but real) gathers + VALU.
//
// Retained: one row per wave, 128-thread blocks, packed (col,val) dwordx2,
// f32x2 packed math, col/val 2-3 groups ahead in ping-pong banks, k/v one
// group ahead, DPP quad reduction, log2(e) folded into q (p = exp2(s)).
// ---------------------------------------------------------------------------
__global__ __launch_bounds__(128) void edge_attn_kernel(
    const __hip_bfloat16* __restrict__ qb, const __hip_bfloat16* __restrict__ kvb,
    const int* __restrict__ row_ptr, const i32x2* __restrict__ cvp,
    float* __restrict__ out) {
  const int wave = threadIdx.x >> 6;
  const int lane = threadIdx.x & 63;
  const int half = lane >> 5;        // which edge of the pair
  const int sl   = lane & 31;        // channel-group lane (8 ch each)
  const int row = blockIdx.x * 2 + wave;
  if (row >= kN) return;

  const int e0 = row_ptr[row];
  const int e1 = row_ptr[row + 1];

  // q channels sl*8 .. sl*8+7, pre-scaled by log2(e) so p = exp2(s)
  const us8 qu = *(const us8*)(qb + (size_t)row * 256 + sl * 8);
  f32x2 qf2[4];
#pragma unroll
  for (int j = 0; j < 4; ++j)
    qf2[j] = f32x2{b2f(qu[2 * j]) * 1.4426950408889634f,
                   b2f(qu[2 * j + 1]) * 1.4426950408889634f};

  float denom = 0.f;
  f32x2 acc2[4];
#pragma unroll
  for (int j = 0; j < 4; ++j) acc2[j] = f32x2{0.f, 0.f};

  if (e0 < e1) {
    const char* kvbL = (const char*)kvb + sl * 16;
    const int elast = e1 - 1;

    u32x4 kS[4], vS[4];        // k/v data for the CURRENT group's 8 edges
    float wS[4];               // val for the current group's 8 edges
    i32x2 cvA[4], cvB[4];      // (col,val) for groups +1 / +2 (ping-pong)

    // ---- warmup ----
    i32x2 c0[4];
#pragma unroll
    for (int j = 0; j < 4; ++j) {        // group 0 cols
      const int ea = min(e0 + 2 * j + half, elast);
      c0[j] = cvp[ea];
    }
#pragma unroll
    for (int j = 0; j < 4; ++j) {        // group 1 cols
      const int eb = min(e0 + 8 + 2 * j + half, elast);
      cvA[j] = cvp[eb];
    }
#pragma unroll
    for (int j = 0; j < 4; ++j) {        // group 2 cols (in flight thru group 0)
      const int ec = min(e0 + 16 + 2 * j + half, elast);
      cvB[j] = cvp[ec];
    }
#pragma unroll
    for (int j = 0; j < 4; ++j) {        // group 0 k/v gathers
      const size_t off = (size_t)c0[j][0] * 1024;
      kS[j] = *(const u32x4*)(kvbL + off);
      vS[j] = *(const u32x4*)(kvbL + off + 512);
      wS[j] = __int_as_float(c0[j][1]);
    }

    // GROUP(EB, CB): consumes edges [EB, EB+8); refills k/v for [EB+8, EB+16)
    // from bank CB (resident); loads (col,val) for [EB+24, EB+32) back into CB.
#define ATTN_GROUP(EB, CB)                                                \
    _Pragma("unroll")                                                     \
    for (int j = 0; j < 4; ++j) {                                         \
      const u32x4 kc = kS[j], vc = vS[j];                                 \
      const float wc = wS[j];                                             \
      {                                                                   \
        const size_t off = (size_t)CB[j][0] * 1024;                       \
        kS[j] = *(const u32x4*)(kvbL + off);                              \
        vS[j] = *(const u32x4*)(kvbL + off + 512);                        \
        wS[j] = __int_as_float(CB[j][1]);                                 \
      }                                                                   \
      {                                                                   \
        const int en = min((EB) + 24 + 2 * j + half, elast);              \
        CB[j] = cvp[en];                                                  \
      }                                                                   \
      f32x2 s2 = qf2[0] * bf2up(kc[0]);                                   \
      s2 += qf2[1] * bf2up(kc[1]);                                        \
      s2 += qf2[2] * bf2up(kc[2]);                                        \
      s2 += qf2[3] * bf2up(kc[3]);                                        \
      float s = s2[0] + s2[1];                                            \
      s = quad_add_xor1(s);                                               \
      s = quad_add_xor2(s);        /* 4-lane head group reduced */        \
      s *= wc;                                                            \
      float p = exp2f(s);                                                 \
      p = (((EB) + 2 * j + half) < e1) ? p : 0.f;                         \
      denom += p;                                                         \
      const f32x2 p2 = {p, p};                                            \
      acc2[0] += p2 * bf2up(vc[0]);                                       \
      acc2[1] += p2 * bf2up(vc[1]);                                       \
      acc2[2] += p2 * bf2up(vc[2]);                                       \
      acc2[3] += p2 * bf2up(vc[3]);                                       \
    }

    // stride-8 loop: exit check BETWEEN groups; banks statically indexed.
    int e = e0;
    for (;;) {
      ATTN_GROUP(e, cvA);
      e += 8; if (e >= e1) break;
      ATTN_GROUP(e, cvB);
      e += 8; if (e >= e1) break;
    }
#undef ATTN_GROUP
  }

  // combine the two halves
  float accs[8];
#pragma unroll
  for (int j = 0; j < 8; ++j) {
    float a = (j & 1) ? acc2[j >> 1][1] : acc2[j >> 1][0];
    accs[j] = a + __shfl_xor(a, 32);
  }
  denom += __shfl_xor(denom, 32);

  const float inv = (denom > 0.f) ? (1.0f / denom) : 0.f;
  // lane's channels cc = sl*8 + j live in head h = sl>>2, dim d=(sl&3)*8+j.
  // This lane writes j = half*4 .. half*4+3; ref channel c = d*8 + h.
  const int h = sl >> 2;
  const int dbase = (sl & 3) * 8 + half * 4;
  float* o = out + (size_t)row * 256 + h;
#pragma unroll
  for (int jj = 0; jj < 4; ++jj)
    o[(dbase + jj) * 8] = accs[half * 4 + jj] * inv;
}

// ---------------------------------------------------------------------------
extern "C" void kernel_launch(void* const* d_in, const int* in_sizes, int n_in,
                              void* d_out, int out_size, void* d_ws, size_t ws_size,
                              hipStream_t stream) {
  const float* h   = (const float*)d_in[0];
  const float* val = (const float*)d_in[1];
  const float* Wq  = (const float*)d_in[2];
  const float* bq  = (const float*)d_in[3];
  const float* Wk  = (const float*)d_in[4];
  const float* bk  = (const float*)d_in[5];
  const float* Wv  = (const float*)d_in[6];
  const float* bv  = (const float*)d_in[7];
  const int* edge_rows = (const int*)d_in[8];
  const int* col_ind   = (const int*)d_in[9];
  float* out = (float*)d_out;

  char* ws = (char*)d_ws;
  __hip_bfloat16* Ah  = (__hip_bfloat16*)ws;                 ws += (size_t)kN * 256 * 2;
  __hip_bfloat16* Bt  = (__hip_bfloat16*)ws;                 ws += (size_t)768 * 256 * 2;
  float*          biasP = (float*)ws;                        ws += 768 * 4;
  __hip_bfloat16* qb  = (__hip_bfloat16*)ws;                 ws += (size_t)kN * 256 * 2;
  __hip_bfloat16* kvb = (__hip_bfloat16*)ws;                 ws += (size_t)kN * 512 * 2;
  int* row_ptr = (int*)ws;                                   ws += ((size_t)(kN + 1) * 4 + 127) & ~127ull;
  i32x2* cv = (i32x2*)ws;

  split_h_kernel<<<kN / 8, 256, 0, stream>>>(h, Ah);          // 8 elems/thread
  build_bt_kernel<<<768, 256, 0, stream>>>(Wq, bq, Wk, bk, Wv, bv, Bt, biasP);
  prep_kernel<<<196 + 782, 256, 0, stream>>>(edge_rows, row_ptr, col_ind, val, cv);

  // 391 M-tiles padded to 49 groups of 8; 6 N-tiles; 8 XCD slots
  gemm_qkv_kernel<<<8 * 6 * 49, 256, 0, stream>>>(Ah, Bt, biasP, qb, kvb);

  edge_attn_kernel<<<(kN + 1) / 2, 128, 0, stream>>>(qb, kvb, row_ptr, cv, out);
}

// Round 8
// 269.468 us; speedup vs baseline: 1.6793x; 1.0030x over previous
//
#include <hip/hip_runtime.h>
#include <hip/hip_bf16.h>
#include <math.h>

static constexpr int kN   = 50000;   // nodes
static constexpr int kE   = 800000;  // edges
static constexpr int kHID = 256;
static constexpr int kHD  = 32;

typedef short bf16x8 __attribute__((ext_vector_type(8)));
typedef float f32x4  __attribute__((ext_vector_type(4)));
typedef float f32x2  __attribute__((ext_vector_type(2)));
typedef unsigned short us8 __attribute__((ext_vector_type(8)));
typedef unsigned int u32x4 __attribute__((ext_vector_type(4)));
typedef int i32x2 __attribute__((ext_vector_type(2)));
typedef int i32x4 __attribute__((ext_vector_type(4)));

__device__ __forceinline__ float b2f(unsigned short u) {
  union { unsigned v; float f; } c; c.v = ((unsigned)u) << 16; return c.f;
}

__device__ __forceinline__ unsigned short f2bu(float f) {
  __hip_bfloat16 b = __float2bfloat16(f);
  union { __hip_bfloat16 b; unsigned short u; } c; c.b = b; return c.u;
}

// unpack u32 holding 2 bf16 (channels 2j, 2j+1) into f32x2
__device__ __forceinline__ f32x2 bf2up(unsigned u) {
  union { unsigned v; float f; } lo, hi;
  lo.v = u << 16; hi.v = u & 0xffff0000u;
  return f32x2{lo.f, hi.f};
}

// quad-local butterfly add via DPP (no LDS round-trip).
__device__ __forceinline__ float quad_add_xor1(float s) {
  union { float f; int i; } a, b;
  a.f = s;
  b.i = __builtin_amdgcn_mov_dpp(a.i, 0xB1, 0xF, 0xF, true);  // quad_perm [1,0,3,2]
  return s + b.f;
}
__device__ __forceinline__ float quad_add_xor2(float s) {
  union { float f; int i; } a, b;
  a.f = s;
  b.i = __builtin_amdgcn_mov_dpp(a.i, 0x4E, 0xF, 0xF, true);  // quad_perm [2,3,0,1]
  return s + b.f;
}

// global -> LDS async copy, 16 B per lane; LDS dest = uniform base + lane*16
__device__ __forceinline__ void load_lds16(const void* g, void* l) {
  __builtin_amdgcn_global_load_lds(
      (const __attribute__((address_space(1))) unsigned int*)(unsigned long long)(uintptr_t)g,
      (__attribute__((address_space(3))) unsigned int*)(unsigned int)(uintptr_t)l,
      16, 0, 0);
}

// ---------------------------------------------------------------------------
// Merged prep: one launch instead of three (saves 2 launch gaps).
//  blocks [0, 6250)        : h -> bf16 (8 elems/thread, 16B stores)
//  blocks [6250, 7018)     : build Bt[768][256] + biasP[768]
//  blocks [7018, 7214)     : row_ptr lower_bound
//  blocks [7214, 7996)     : pack (col,val) int2 cv[]
// All four parts are independent (write disjoint buffers).
// ---------------------------------------------------------------------------
__global__ void prep_all_kernel(
    const float* __restrict__ h, __hip_bfloat16* __restrict__ Ah,
    const float* __restrict__ Wq, const float* __restrict__ bq,
    const float* __restrict__ Wk, const float* __restrict__ bk,
    const float* __restrict__ Wv, const float* __restrict__ bv,
    __hip_bfloat16* __restrict__ Bt, float* __restrict__ biasP,
    const int* __restrict__ er, int* __restrict__ rp,
    const int* __restrict__ ci, const float* __restrict__ vl,
    i32x2* __restrict__ cv) {
  int b = blockIdx.x;
  if (b < 6250) {                      // ---- split_h ----
    int idx = b * 256 + threadIdx.x;
    const f32x4* hp = (const f32x4*)(h + (size_t)idx * 8);
    f32x4 a = hp[0], c = hp[1];
    us8 o;
    o[0] = f2bu(a[0]); o[1] = f2bu(a[1]); o[2] = f2bu(a[2]); o[3] = f2bu(a[3]);
    o[4] = f2bu(c[0]); o[5] = f2bu(c[1]); o[6] = f2bu(c[2]); o[7] = f2bu(c[3]);
    *(us8*)(Ah + (size_t)idx * 8) = o;
    return;
  }
  b -= 6250;
  if (b < 768) {                       // ---- build_bt ----
    const int n  = b;
    const int kk = threadIdx.x;
    const int g  = n >> 8;
    const int cc = n & 255;
    const int c  = ((cc & 31) << 3) + (cc >> 5);
    const float scale = (g == 0) ? 0.17677669529663689f : 1.0f;
    const float* W = (g == 0) ? Wq : ((g == 1) ? Wk : Wv);
    Bt[n * 256 + kk] = __float2bfloat16(W[kk * 256 + c] * scale);
    if (kk == 0) {
      const float* bb = (g == 0) ? bq : ((g == 1) ? bk : bv);
      biasP[n] = bb[c] * scale;
    }
    return;
  }
  b -= 768;
  if (b < 196) {                       // ---- row_ptr ----
    int i = b * 256 + threadIdx.x;
    if (i > kN) return;
    int lo = 0, hi = kE;
    while (lo < hi) {
      int mid = (lo + hi) >> 1;
      if (er[mid] < i) lo = mid + 1; else hi = mid;
    }
    rp[i] = lo;
    return;
  }
  b -= 196;
  {                                    // ---- cv pack ----
    const int e4 = (b * 256 + threadIdx.x) * 4;
    if (e4 < kE) {
      i32x4 c = *(const i32x4*)(ci + e4);
      f32x4 w = *(const f32x4*)(vl + e4);
      i32x4 o0 = {c[0], __float_as_int(w[0]), c[1], __float_as_int(w[1])};
      i32x4 o1 = {c[2], __float_as_int(w[2]), c[3], __float_as_int(w[3])};
      *(i32x4*)(cv + e4)     = o0;
      *(i32x4*)(cv + e4 + 2) = o1;
    }
  }
}

// ---------------------------------------------------------------------------
// Fused MFMA GEMM: C[M=50000][768] = A[M][256] * Bt[768][256]^T + bias.
// 128x128 tile, BK=64, 256 threads (4 waves 2x2), global_load_lds staging,
// XOR-swizzled LDS (conflict-free). 1-D grid with XCD-aware decode: all 6
// N-tiles sharing an A-panel land on the SAME XCD consecutively (A in L2).
// Epilogue: C tile staged bf16 in LDS (padded), stored as coalesced 16B chunks.
// ---------------------------------------------------------------------------
__global__ __launch_bounds__(256) void gemm_qkv_kernel(
    const __hip_bfloat16* __restrict__ Ah,
    const __hip_bfloat16* __restrict__ Bt, const float* __restrict__ biasP,
    __hip_bfloat16* __restrict__ qb, __hip_bfloat16* __restrict__ kvb) {
  __shared__ __align__(16) char smemRaw[34816];   // max(32 KB tiles, 128*136*2 C)
  short* smemA = (short*)smemRaw;                 // [128][64] 16B-chunk swizzled
  short* smemB = (short*)(smemRaw + 16384);
  short* smemC = (short*)smemRaw;                 // [128][136] padded C tile

  // XCD-aware decode: L = xcd + 8*(n + 6*mg), m-tile = mg*8 + xcd
  const int L   = blockIdx.x;
  const int xcd = L & 7;
  const int t   = L >> 3;
  const int nt  = t % 6;
  const int mg  = t / 6;
  const int mt  = mg * 8 + xcd;
  if (mt >= 391) return;
  const int colBase = nt * 128;
  const int rowBase = mt * 128;

  const int tid  = threadIdx.x;
  const int wave = tid >> 6;
  const int lane = tid & 63;
  const int wm = wave & 1;            // M half of tile
  const int wn = wave >> 1;           // N half

  f32x4 acc[4][4];
#pragma unroll
  for (int i = 0; i < 4; ++i)
#pragma unroll
    for (int j = 0; j < 4; ++j) acc[i][j] = f32x4{0.f, 0.f, 0.f, 0.f};

  for (int k0 = 0; k0 < 256; k0 += 64) {
    __syncthreads();
    // ---- stage A tile: 128 rows x 64 k (bf16) = 16 KB, 4 calls/wave
#pragma unroll
    for (int j = 0; j < 4; ++j) {
      int s = (wave * 4 + j) * 64 + lane;
      int r = s >> 3, cp = s & 7;
      int c = cp ^ (r & 7);
      int grow = rowBase + r;
      grow = grow < kN ? grow : kN - 1;   // clamp (garbage rows masked at store)
      const char* gp = (const char*)Ah + (size_t)grow * 512 + k0 * 2 + c * 16;
      load_lds16(gp, (char*)smemA + (wave * 4 + j) * 1024);
    }
    // ---- stage B tile: 128 n-rows x 64 k = 16 KB
#pragma unroll
    for (int j = 0; j < 4; ++j) {
      int s = (wave * 4 + j) * 64 + lane;
      int r = s >> 3, cp = s & 7;
      int c = cp ^ (r & 7);
      const char* gp = (const char*)Bt + (size_t)(colBase + r) * 512 + k0 * 2 + c * 16;
      load_lds16(gp, (char*)smemB + (wave * 4 + j) * 1024);
    }
    __syncthreads();

    const int rq = lane & 15, qd = lane >> 4;
#pragma unroll
    for (int ks = 0; ks < 2; ++ks) {
      bf16x8 af[4], bfr[4];
#pragma unroll
      for (int mi = 0; mi < 4; ++mi) {
        int r = wm * 64 + mi * 16 + rq;
        int c = (ks * 4 + qd) ^ (r & 7);
        af[mi] = *(const bf16x8*)&smemA[r * 64 + c * 8];
      }
#pragma unroll
      for (int nj = 0; nj < 4; ++nj) {
        int r = wn * 64 + nj * 16 + rq;
        int c = (ks * 4 + qd) ^ (r & 7);
        bfr[nj] = *(const bf16x8*)&smemB[r * 64 + c * 8];
      }
#pragma unroll
      for (int mi = 0; mi < 4; ++mi)
#pragma unroll
        for (int nj = 0; nj < 4; ++nj)
          acc[mi][nj] = __builtin_amdgcn_mfma_f32_16x16x32_bf16(
              af[mi], bfr[nj], acc[mi][nj], 0, 0, 0);
    }
  }

  // ---- epilogue: stage bf16 C tile in LDS, then coalesced stores.
  // C frag layout: row=(lane>>4)*4+reg, col=lane&15 (verified m89/m91).
  __syncthreads();   // tiles no longer needed; reuse as smemC
#pragma unroll
  for (int nj = 0; nj < 4; ++nj) {
    const int cl = wn * 64 + nj * 16 + (lane & 15);
    const float bb = biasP[colBase + cl];
#pragma unroll
    for (int mi = 0; mi < 4; ++mi) {
      const int rl = wm * 64 + mi * 16 + (lane >> 4) * 4;
#pragma unroll
      for (int reg = 0; reg < 4; ++reg) {
        smemC[(rl + reg) * 136 + cl] = (short)f2bu(acc[mi][nj][reg] + bb);
      }
    }
  }
  __syncthreads();

  const int g = colBase >> 8;   // block-uniform: 0=q 1=k 2=v
#pragma unroll
  for (int it = 0; it < 8; ++it) {
    const int r   = it * 16 + (tid >> 4);      // 0..127
    const int c16 = tid & 15;                  // 16B chunk within row
    const int row = rowBase + r;
    if (row < kN) {
      bf16x8 vls = *(const bf16x8*)&smemC[r * 136 + c16 * 8];
      const int cc = (colBase & 255) + c16 * 8;
      __hip_bfloat16* dst =
          (g == 0) ? (qb + (size_t)row * 256 + cc)
                   : (kvb + (size_t)row * 512 + (g == 2 ? 256 : 0) + cc);
      *(bf16x8*)dst = vls;
    }
  }
}

// ---------------------------------------------------------------------------
// Fused SDDMM + segment softmax + SpMM (v7).
//
// v7 = v6 with a 2-GROUP-DEEP k/v pipeline (Little's law fix): k/v gathers
// for group g are issued during group g-2 (~500 cy of compute cover vs
// ~250 before; gather latency is 200-900 cy, 44% of gather bytes HBM-miss).
// Static register banks kSa/kSb, vSa/vSb, wSa/wSb alternate per group
// (unroll-2 loop, all indices compile-time -> no scratch). cv (col,val)
// banks cvA/cvB are refilled 2 groups ahead of their next use (EB+32).
//
// Retained: one row per wave, 128-thread blocks, stride-8 tail granularity,
// packed (col,val) dwordx2, f32x2 packed math, DPP quad reduction, log2(e)
// folded into q (p = exp2(s)).
// ---------------------------------------------------------------------------
__global__ __launch_bounds__(128) void edge_attn_kernel(
    const __hip_bfloat16* __restrict__ qb, const __hip_bfloat16* __restrict__ kvb,
    const int* __restrict__ row_ptr, const i32x2* __restrict__ cvp,
    float* __restrict__ out) {
  const int wave = threadIdx.x >> 6;
  const int lane = threadIdx.x & 63;
  const int half = lane >> 5;        // which edge of the pair
  const int sl   = lane & 31;        // channel-group lane (8 ch each)
  const int row = blockIdx.x * 2 + wave;
  if (row >= kN) return;

  const int e0 = row_ptr[row];
  const int e1 = row_ptr[row + 1];

  // q channels sl*8 .. sl*8+7, pre-scaled by log2(e) so p = exp2(s)
  const us8 qu = *(const us8*)(qb + (size_t)row * 256 + sl * 8);
  f32x2 qf2[4];
#pragma unroll
  for (int j = 0; j < 4; ++j)
    qf2[j] = f32x2{b2f(qu[2 * j]) * 1.4426950408889634f,
                   b2f(qu[2 * j + 1]) * 1.4426950408889634f};

  float denom = 0.f;
  f32x2 acc2[4];
#pragma unroll
  for (int j = 0; j < 4; ++j) acc2[j] = f32x2{0.f, 0.f};

  if (e0 < e1) {
    const char* kvbL = (const char*)kvb + sl * 16;
    const int elast = e1 - 1;

    u32x4 kSa[4], vSa[4], kSb[4], vSb[4];   // 2-deep k/v banks
    float wSa[4], wSb[4];
    i32x2 cvA[4], cvB[4];                    // (col,val) address banks

    // ---- warmup: cols for groups 0..3; k/v gathers for groups 0,1 ----
    i32x2 c00[4], c01[4];
#pragma unroll
    for (int j = 0; j < 4; ++j) c00[j] = cvp[min(e0 +      2 * j + half, elast)];
#pragma unroll
    for (int j = 0; j < 4; ++j) c01[j] = cvp[min(e0 +  8 + 2 * j + half, elast)];
#pragma unroll
    for (int j = 0; j < 4; ++j) cvA[j] = cvp[min(e0 + 16 + 2 * j + half, elast)];
#pragma unroll
    for (int j = 0; j < 4; ++j) cvB[j] = cvp[min(e0 + 24 + 2 * j + half, elast)];
#pragma unroll
    for (int j = 0; j < 4; ++j) {            // group 0 k/v
      const size_t off = (size_t)c00[j][0] * 1024;
      kSa[j] = *(const u32x4*)(kvbL + off);
      vSa[j] = *(const u32x4*)(kvbL + off + 512);
      wSa[j] = __int_as_float(c00[j][1]);
    }
#pragma unroll
    for (int j = 0; j < 4; ++j) {            // group 1 k/v
      const size_t off = (size_t)c01[j][0] * 1024;
      kSb[j] = *(const u32x4*)(kvbL + off);
      vSb[j] = *(const u32x4*)(kvbL + off + 512);
      wSb[j] = __int_as_float(c01[j][1]);
    }

    // GROUP(EB, KS,VS,WS, CV): consumes edges [EB, EB+8) from KS/VS/WS
    // (loaded 2 groups ago); issues k/v for [EB+16, EB+24) from CV
    // (resident); refills CV with cols for [EB+32, EB+40) (next read at
    // group EB+16).
#define ATTN_GROUP(EB, KS, VS, WS, CV)                                    \
    _Pragma("unroll")                                                     \
    for (int j = 0; j < 4; ++j) {                                         \
      const u32x4 kc = KS[j], vc = VS[j];                                 \
      const float wc = WS[j];                                             \
      {                                                                   \
        const size_t off = (size_t)CV[j][0] * 1024;                       \
        KS[j] = *(const u32x4*)(kvbL + off);                              \
        VS[j] = *(const u32x4*)(kvbL + off + 512);                        \
        WS[j] = __int_as_float(CV[j][1]);                                 \
      }                                                                   \
      {                                                                   \
        const int en = min((EB) + 32 + 2 * j + half, elast);              \
        CV[j] = cvp[en];                                                  \
      }                                                                   \
      f32x2 s2 = qf2[0] * bf2up(kc[0]);                                   \
      s2 += qf2[1] * bf2up(kc[1]);                                        \
      s2 += qf2[2] * bf2up(kc[2]);                                        \
      s2 += qf2[3] * bf2up(kc[3]);                                        \
      float s = s2[0] + s2[1];                                            \
      s = quad_add_xor1(s);                                               \
      s = quad_add_xor2(s);        /* 4-lane head group reduced */        \
      s *= wc;                                                            \
      float p = exp2f(s);                                                 \
      p = (((EB) + 2 * j + half) < e1) ? p : 0.f;                         \
      denom += p;                                                         \
      const f32x2 p2 = {p, p};                                            \
      acc2[0] += p2 * bf2up(vc[0]);                                       \
      acc2[1] += p2 * bf2up(vc[1]);                                       \
      acc2[2] += p2 * bf2up(vc[2]);                                       \
      acc2[3] += p2 * bf2up(vc[3]);                                       \
    }

    // stride-8 loop: exit check BETWEEN groups; banks statically indexed.
    int e = e0;
    for (;;) {
      ATTN_GROUP(e, kSa, vSa, wSa, cvA);
      e += 8; if (e >= e1) break;
      ATTN_GROUP(e, kSb, vSb, wSb, cvB);
      e += 8; if (e >= e1) break;
    }
#undef ATTN_GROUP
  }

  // combine the two halves
  float accs[8];
#pragma unroll
  for (int j = 0; j < 8; ++j) {
    float a = (j & 1) ? acc2[j >> 1][1] : acc2[j >> 1][0];
    accs[j] = a + __shfl_xor(a, 32);
  }
  denom += __shfl_xor(denom, 32);

  const float inv = (denom > 0.f) ? (1.0f / denom) : 0.f;
  // lane's channels cc = sl*8 + j live in head h = sl>>2, dim d=(sl&3)*8+j.
  // This lane writes j = half*4 .. half*4+3; ref channel c = d*8 + h.
  const int h = sl >> 2;
  const int dbase = (sl & 3) * 8 + half * 4;
  float* o = out + (size_t)row * 256 + h;
#pragma unroll
  for (int jj = 0; jj < 4; ++jj)
    o[(dbase + jj) * 8] = accs[half * 4 + jj] * inv;
}

// ---------------------------------------------------------------------------
extern "C" void kernel_launch(void* const* d_in, const int* in_sizes, int n_in,
                              void* d_out, int out_size, void* d_ws, size_t ws_size,
                              hipStream_t stream) {
  const float* h   = (const float*)d_in[0];
  const float* val = (const float*)d_in[1];
  const float* Wq  = (const float*)d_in[2];
  const float* bq  = (const float*)d_in[3];
  const float* Wk  = (const float*)d_in[4];
  const float* bk  = (const float*)d_in[5];
  const float* Wv  = (const float*)d_in[6];
  const float* bv  = (const float*)d_in[7];
  const int* edge_rows = (const int*)d_in[8];
  const int* col_ind   = (const int*)d_in[9];
  float* out = (float*)d_out;

  char* ws = (char*)d_ws;
  __hip_bfloat16* Ah  = (__hip_bfloat16*)ws;                 ws += (size_t)kN * 256 * 2;
  __hip_bfloat16* Bt  = (__hip_bfloat16*)ws;                 ws += (size_t)768 * 256 * 2;
  float*          biasP = (float*)ws;                        ws += 768 * 4;
  __hip_bfloat16* qb  = (__hip_bfloat16*)ws;                 ws += (size_t)kN * 256 * 2;
  __hip_bfloat16* kvb = (__hip_bfloat16*)ws;                 ws += (size_t)kN * 512 * 2;
  int* row_ptr = (int*)ws;                                   ws += ((size_t)(kN + 1) * 4 + 127) & ~127ull;
  i32x2* cv = (i32x2*)ws;

  // merged prep: split_h + build_bt + row_ptr + cv pack in ONE launch
  prep_all_kernel<<<6250 + 768 + 196 + 782, 256, 0, stream>>>(
      h, Ah, Wq, bq, Wk, bk, Wv, bv, Bt, biasP,
      edge_rows, row_ptr, col_ind, val, cv);

  // 391 M-tiles padded to 49 groups of 8; 6 N-tiles; 8 XCD slots
  gemm_qkv_kernel<<<8 * 6 * 49, 256, 0, stream>>>(Ah, Bt, biasP, qb, kvb);

  edge_attn_kernel<<<(kN + 1) / 2, 128, 0, stream>>>(qb, kvb, row_ptr, cv, out);
}

// Round 9
// 266.590 us; speedup vs baseline: 1.6974x; 1.0108x over previous
//
#include <hip/hip_runtime.h>
#include <hip/hip_bf16.h>
#include <math.h>

static constexpr int kN   = 50000;   // nodes
static constexpr int kE   = 800000;  // edges
static constexpr int kHID = 256;
static constexpr int kHD  = 32;

typedef short bf16x8 __attribute__((ext_vector_type(8)));
typedef float f32x4  __attribute__((ext_vector_type(4)));
typedef float f32x2  __attribute__((ext_vector_type(2)));
typedef unsigned short us8 __attribute__((ext_vector_type(8)));
typedef unsigned int u32x4 __attribute__((ext_vector_type(4)));
typedef int i32x2 __attribute__((ext_vector_type(2)));
typedef int i32x4 __attribute__((ext_vector_type(4)));

__device__ __forceinline__ float b2f(unsigned short u) {
  union { unsigned v; float f; } c; c.v = ((unsigned)u) << 16; return c.f;
}

__device__ __forceinline__ unsigned short f2bu(float f) {
  __hip_bfloat16 b = __float2bfloat16(f);
  union { __hip_bfloat16 b; unsigned short u; } c; c.b = b; return c.u;
}

// unpack u32 holding 2 bf16 (channels 2j, 2j+1) into f32x2
__device__ __forceinline__ f32x2 bf2up(unsigned u) {
  union { unsigned v; float f; } lo, hi;
  lo.v = u << 16; hi.v = u & 0xffff0000u;
  return f32x2{lo.f, hi.f};
}

// quad-local butterfly add via DPP (no LDS round-trip).
__device__ __forceinline__ float quad_add_xor1(float s) {
  union { float f; int i; } a, b;
  a.f = s;
  b.i = __builtin_amdgcn_mov_dpp(a.i, 0xB1, 0xF, 0xF, true);  // quad_perm [1,0,3,2]
  return s + b.f;
}
__device__ __forceinline__ float quad_add_xor2(float s) {
  union { float f; int i; } a, b;
  a.f = s;
  b.i = __builtin_amdgcn_mov_dpp(a.i, 0x4E, 0xF, 0xF, true);  // quad_perm [2,3,0,1]
  return s + b.f;
}

// global -> LDS async copy, 16 B per lane; LDS dest = uniform base + lane*16
__device__ __forceinline__ void load_lds16(const void* g, void* l) {
  __builtin_amdgcn_global_load_lds(
      (const __attribute__((address_space(1))) unsigned int*)(unsigned long long)(uintptr_t)g,
      (__attribute__((address_space(3))) unsigned int*)(unsigned int)(uintptr_t)l,
      16, 0, 0);
}

// ---------------------------------------------------------------------------
// Merged prep: one launch.
//  blocks [0, 6250)        : h -> bf16 (8 elems/thread, 16B stores)
//  blocks [6250, 7018)     : build Bt[768][256] + biasP[768]
//  blocks [7018, 7214)     : row_ptr lower_bound
//  blocks [7214, 7996)     : pack (col,val) int2 cv[]
// ---------------------------------------------------------------------------
__global__ void prep_all_kernel(
    const float* __restrict__ h, __hip_bfloat16* __restrict__ Ah,
    const float* __restrict__ Wq, const float* __restrict__ bq,
    const float* __restrict__ Wk, const float* __restrict__ bk,
    const float* __restrict__ Wv, const float* __restrict__ bv,
    __hip_bfloat16* __restrict__ Bt, float* __restrict__ biasP,
    const int* __restrict__ er, int* __restrict__ rp,
    const int* __restrict__ ci, const float* __restrict__ vl,
    i32x2* __restrict__ cv) {
  int b = blockIdx.x;
  if (b < 6250) {                      // ---- split_h ----
    int idx = b * 256 + threadIdx.x;
    const f32x4* hp = (const f32x4*)(h + (size_t)idx * 8);
    f32x4 a = hp[0], c = hp[1];
    us8 o;
    o[0] = f2bu(a[0]); o[1] = f2bu(a[1]); o[2] = f2bu(a[2]); o[3] = f2bu(a[3]);
    o[4] = f2bu(c[0]); o[5] = f2bu(c[1]); o[6] = f2bu(c[2]); o[7] = f2bu(c[3]);
    *(us8*)(Ah + (size_t)idx * 8) = o;
    return;
  }
  b -= 6250;
  if (b < 768) {                       // ---- build_bt ----
    const int n  = b;
    const int kk = threadIdx.x;
    const int g  = n >> 8;
    const int cc = n & 255;
    const int c  = ((cc & 31) << 3) + (cc >> 5);
    const float scale = (g == 0) ? 0.17677669529663689f : 1.0f;
    const float* W = (g == 0) ? Wq : ((g == 1) ? Wk : Wv);
    Bt[n * 256 + kk] = __float2bfloat16(W[kk * 256 + c] * scale);
    if (kk == 0) {
      const float* bb = (g == 0) ? bq : ((g == 1) ? bk : bv);
      biasP[n] = bb[c] * scale;
    }
    return;
  }
  b -= 768;
  if (b < 196) {                       // ---- row_ptr ----
    int i = b * 256 + threadIdx.x;
    if (i > kN) return;
    int lo = 0, hi = kE;
    while (lo < hi) {
      int mid = (lo + hi) >> 1;
      if (er[mid] < i) lo = mid + 1; else hi = mid;
    }
    rp[i] = lo;
    return;
  }
  b -= 196;
  {                                    // ---- cv pack ----
    const int e4 = (b * 256 + threadIdx.x) * 4;
    if (e4 < kE) {
      i32x4 c = *(const i32x4*)(ci + e4);
      f32x4 w = *(const f32x4*)(vl + e4);
      i32x4 o0 = {c[0], __float_as_int(w[0]), c[1], __float_as_int(w[1])};
      i32x4 o1 = {c[2], __float_as_int(w[2]), c[3], __float_as_int(w[3])};
      *(i32x4*)(cv + e4)     = o0;
      *(i32x4*)(cv + e4 + 2) = o1;
    }
  }
}

// ---------------------------------------------------------------------------
// Fused MFMA GEMM (v8): C[50000][768] = A[50000][256] * Bt[768][256]^T + bias.
// K=256 is tiny (4 K-steps) -> the old single-buffer loop exposed the FULL
// stage latency 4x per block (vmcnt(0) drain before each barrier; compute
// only ~640 cy/step). v8: 64 KB LDS DOUBLE-BUFFER + T3-minimum 2-phase
// pipeline: issue next tile's global_load_lds BEFORE computing the current
// tile; ONE barrier per K-step (its vmcnt drain lands AFTER compute, so
// stage latency hides under MFMA). 2 blocks/CU co-resident (128 KB LDS).
// XCD-aware decode unchanged; epilogue unchanged (C reuses LDS after bar).
// ---------------------------------------------------------------------------
__global__ __launch_bounds__(256) void gemm_qkv_kernel(
    const __hip_bfloat16* __restrict__ Ah,
    const __hip_bfloat16* __restrict__ Bt, const float* __restrict__ biasP,
    __hip_bfloat16* __restrict__ qb, __hip_bfloat16* __restrict__ kvb) {
  __shared__ __align__(16) char smemRaw[65536];   // A0|B0|A1|B1 x 16 KB
  short* smemC = (short*)smemRaw;                 // [128][136] C tile (epilogue)

  // XCD-aware decode: L = xcd + 8*(n + 6*mg), m-tile = mg*8 + xcd
  const int L   = blockIdx.x;
  const int xcd = L & 7;
  const int t_  = L >> 3;
  const int nt  = t_ % 6;
  const int mg  = t_ / 6;
  const int mt  = mg * 8 + xcd;
  if (mt >= 391) return;
  const int colBase = nt * 128;
  const int rowBase = mt * 128;

  const int tid  = threadIdx.x;
  const int wave = tid >> 6;
  const int lane = tid & 63;
  const int wm = wave & 1;            // M half of tile
  const int wn = wave >> 1;           // N half

  f32x4 acc[4][4];
#pragma unroll
  for (int i = 0; i < 4; ++i)
#pragma unroll
    for (int j = 0; j < 4; ++j) acc[i][j] = f32x4{0.f, 0.f, 0.f, 0.f};

  // stage A+B tiles for K-step base K0 into buffer BUF (async, no wait)
#define STAGE(BUF, K0)                                                      \
  {                                                                         \
    char* dA = smemRaw + (BUF) * 32768;                                     \
    char* dB = dA + 16384;                                                  \
    _Pragma("unroll")                                                       \
    for (int j = 0; j < 4; ++j) {                                           \
      int s = (wave * 4 + j) * 64 + lane;                                   \
      int r = s >> 3, cp = s & 7;                                           \
      int c = cp ^ (r & 7);                                                 \
      int grow = rowBase + r;                                               \
      grow = grow < kN ? grow : kN - 1;                                     \
      load_lds16((const char*)Ah + (size_t)grow * 512 + (K0) * 2 + c * 16,  \
                 dA + (wave * 4 + j) * 1024);                               \
      load_lds16((const char*)Bt + (size_t)(colBase + r) * 512 + (K0) * 2 + c * 16, \
                 dB + (wave * 4 + j) * 1024);                               \
    }                                                                       \
  }

  STAGE(0, 0);
  __syncthreads();                     // tile 0 resident

  const int rq = lane & 15, qd = lane >> 4;
#pragma unroll
  for (int t = 0; t < 4; ++t) {
    if (t < 3) STAGE((t + 1) & 1, (t + 1) * 64);   // prefetch next tile
    const short* sA = (const short*)(smemRaw + (t & 1) * 32768);
    const short* sB = sA + 8192;                    // +16384 bytes
#pragma unroll
    for (int ks = 0; ks < 2; ++ks) {
      bf16x8 af[4], bfr[4];
#pragma unroll
      for (int mi = 0; mi < 4; ++mi) {
        int r = wm * 64 + mi * 16 + rq;
        int c = (ks * 4 + qd) ^ (r & 7);
        af[mi] = *(const bf16x8*)&sA[r * 64 + c * 8];
      }
#pragma unroll
      for (int nj = 0; nj < 4; ++nj) {
        int r = wn * 64 + nj * 16 + rq;
        int c = (ks * 4 + qd) ^ (r & 7);
        bfr[nj] = *(const bf16x8*)&sB[r * 64 + c * 8];
      }
#pragma unroll
      for (int mi = 0; mi < 4; ++mi)
#pragma unroll
        for (int nj = 0; nj < 4; ++nj)
          acc[mi][nj] = __builtin_amdgcn_mfma_f32_16x16x32_bf16(
              af[mi], bfr[nj], acc[mi][nj], 0, 0, 0);
    }
    __syncthreads();   // drains prefetch (vmcnt) AFTER compute; next tile ready
  }
#undef STAGE

  // ---- epilogue: stage bf16 C tile in LDS, then coalesced stores.
  // C frag layout: row=(lane>>4)*4+reg, col=lane&15 (verified m89/m91).
  // (last barrier above already separates tile reads from C overwrite)
#pragma unroll
  for (int nj = 0; nj < 4; ++nj) {
    const int cl = wn * 64 + nj * 16 + (lane & 15);
    const float bb = biasP[colBase + cl];
#pragma unroll
    for (int mi = 0; mi < 4; ++mi) {
      const int rl = wm * 64 + mi * 16 + (lane >> 4) * 4;
#pragma unroll
      for (int reg = 0; reg < 4; ++reg) {
        smemC[(rl + reg) * 136 + cl] = (short)f2bu(acc[mi][nj][reg] + bb);
      }
    }
  }
  __syncthreads();

  const int g = colBase >> 8;   // block-uniform: 0=q 1=k 2=v
#pragma unroll
  for (int it = 0; it < 8; ++it) {
    const int r   = it * 16 + (tid >> 4);      // 0..127
    const int c16 = tid & 15;                  // 16B chunk within row
    const int row = rowBase + r;
    if (row < kN) {
      bf16x8 vls = *(const bf16x8*)&smemC[r * 136 + c16 * 8];
      const int cc = (colBase & 255) + c16 * 8;
      __hip_bfloat16* dst =
          (g == 0) ? (qb + (size_t)row * 256 + cc)
                   : (kvb + (size_t)row * 512 + (g == 2 ? 256 : 0) + cc);
      *(bf16x8*)dst = vls;
    }
  }
}

// ---------------------------------------------------------------------------
// Fused SDDMM + segment softmax + SpMM — exact v6 (best measured: 114.7 us,
// VGPR 60, occupancy 40%). One row per wave, 128-thread blocks, stride-8
// tail granularity, packed (col,val) dwordx2, f32x2 packed math, col/val
// 2-3 groups ahead in ping-pong banks, k/v one group ahead, DPP quad
// reduction, log2(e) folded into q (p = exp2(s)).
// ---------------------------------------------------------------------------
__global__ __launch_bounds__(128) void edge_attn_kernel(
    const __hip_bfloat16* __restrict__ qb, const __hip_bfloat16* __restrict__ kvb,
    const int* __restrict__ row_ptr, const i32x2* __restrict__ cvp,
    float* __restrict__ out) {
  const int wave = threadIdx.x >> 6;
  const int lane = threadIdx.x & 63;
  const int half = lane >> 5;        // which edge of the pair
  const int sl   = lane & 31;        // channel-group lane (8 ch each)
  const int row = blockIdx.x * 2 + wave;
  if (row >= kN) return;

  const int e0 = row_ptr[row];
  const int e1 = row_ptr[row + 1];

  // q channels sl*8 .. sl*8+7, pre-scaled by log2(e) so p = exp2(s)
  const us8 qu = *(const us8*)(qb + (size_t)row * 256 + sl * 8);
  f32x2 qf2[4];
#pragma unroll
  for (int j = 0; j < 4; ++j)
    qf2[j] = f32x2{b2f(qu[2 * j]) * 1.4426950408889634f,
                   b2f(qu[2 * j + 1]) * 1.4426950408889634f};

  float denom = 0.f;
  f32x2 acc2[4];
#pragma unroll
  for (int j = 0; j < 4; ++j) acc2[j] = f32x2{0.f, 0.f};

  if (e0 < e1) {
    const char* kvbL = (const char*)kvb + sl * 16;
    const int elast = e1 - 1;

    u32x4 kS[4], vS[4];        // k/v data for the CURRENT group's 8 edges
    float wS[4];               // val for the current group's 8 edges
    i32x2 cvA[4], cvB[4];      // (col,val) for groups +1 / +2 (ping-pong)

    // ---- warmup ----
    i32x2 c0[4];
#pragma unroll
    for (int j = 0; j < 4; ++j) {        // group 0 cols
      const int ea = min(e0 + 2 * j + half, elast);
      c0[j] = cvp[ea];
    }
#pragma unroll
    for (int j = 0; j < 4; ++j) {        // group 1 cols
      const int eb = min(e0 + 8 + 2 * j + half, elast);
      cvA[j] = cvp[eb];
    }
#pragma unroll
    for (int j = 0; j < 4; ++j) {        // group 2 cols (in flight thru group 0)
      const int ec = min(e0 + 16 + 2 * j + half, elast);
      cvB[j] = cvp[ec];
    }
#pragma unroll
    for (int j = 0; j < 4; ++j) {        // group 0 k/v gathers
      const size_t off = (size_t)c0[j][0] * 1024;
      kS[j] = *(const u32x4*)(kvbL + off);
      vS[j] = *(const u32x4*)(kvbL + off + 512);
      wS[j] = __int_as_float(c0[j][1]);
    }

    // GROUP(EB, CB): consumes edges [EB, EB+8); refills k/v for [EB+8, EB+16)
    // from bank CB (resident); loads (col,val) for [EB+24, EB+32) back into CB.
#define ATTN_GROUP(EB, CB)                                                \
    _Pragma("unroll")                                                     \
    for (int j = 0; j < 4; ++j) {                                         \
      const u32x4 kc = kS[j], vc = vS[j];                                 \
      const float wc = wS[j];                                             \
      {                                                                   \
        const size_t off = (size_t)CB[j][0] * 1024;                       \
        kS[j] = *(const u32x4*)(kvbL + off);                              \
        vS[j] = *(const u32x4*)(kvbL + off + 512);                        \
        wS[j] = __int_as_float(CB[j][1]);                                 \
      }                                                                   \
      {                                                                   \
        const int en = min((EB) + 24 + 2 * j + half, elast);              \
        CB[j] = cvp[en];                                                  \
      }                                                                   \
      f32x2 s2 = qf2[0] * bf2up(kc[0]);                                   \
      s2 += qf2[1] * bf2up(kc[1]);                                        \
      s2 += qf2[2] * bf2up(kc[2]);                                        \
      s2 += qf2[3] * bf2up(kc[3]);                                        \
      float s = s2[0] + s2[1];                                            \
      s = quad_add_xor1(s);                                               \
      s = quad_add_xor2(s);        /* 4-lane head group reduced */        \
      s *= wc;                                                            \
      float p = exp2f(s);                                                 \
      p = (((EB) + 2 * j + half) < e1) ? p : 0.f;                         \
      denom += p;                                                         \
      const f32x2 p2 = {p, p};                                            \
      acc2[0] += p2 * bf2up(vc[0]);                                       \
      acc2[1] += p2 * bf2up(vc[1]);                                       \
      acc2[2] += p2 * bf2up(vc[2]);                                       \
      acc2[3] += p2 * bf2up(vc[3]);                                       \
    }

    // stride-8 loop: exit check BETWEEN groups; banks statically indexed.
    int e = e0;
    for (;;) {
      ATTN_GROUP(e, cvA);
      e += 8; if (e >= e1) break;
      ATTN_GROUP(e, cvB);
      e += 8; if (e >= e1) break;
    }
#undef ATTN_GROUP
  }

  // combine the two halves
  float accs[8];
#pragma unroll
  for (int j = 0; j < 8; ++j) {
    float a = (j & 1) ? acc2[j >> 1][1] : acc2[j >> 1][0];
    accs[j] = a + __shfl_xor(a, 32);
  }
  denom += __shfl_xor(denom, 32);

  const float inv = (denom > 0.f) ? (1.0f / denom) : 0.f;
  // lane's channels cc = sl*8 + j live in head h = sl>>2, dim d=(sl&3)*8+j.
  // This lane writes j = half*4 .. half*4+3; ref channel c = d*8 + h.
  const int h = sl >> 2;
  const int dbase = (sl & 3) * 8 + half * 4;
  float* o = out + (size_t)row * 256 + h;
#pragma unroll
  for (int jj = 0; jj < 4; ++jj)
    o[(dbase + jj) * 8] = accs[half * 4 + jj] * inv;
}

// ---------------------------------------------------------------------------
extern "C" void kernel_launch(void* const* d_in, const int* in_sizes, int n_in,
                              void* d_out, int out_size, void* d_ws, size_t ws_size,
                              hipStream_t stream) {
  const float* h   = (const float*)d_in[0];
  const float* val = (const float*)d_in[1];
  const float* Wq  = (const float*)d_in[2];
  const float* bq  = (const float*)d_in[3];
  const float* Wk  = (const float*)d_in[4];
  const float* bk  = (const float*)d_in[5];
  const float* Wv  = (const float*)d_in[6];
  const float* bv  = (const float*)d_in[7];
  const int* edge_rows = (const int*)d_in[8];
  const int* col_ind   = (const int*)d_in[9];
  float* out = (float*)d_out;

  char* ws = (char*)d_ws;
  __hip_bfloat16* Ah  = (__hip_bfloat16*)ws;                 ws += (size_t)kN * 256 * 2;
  __hip_bfloat16* Bt  = (__hip_bfloat16*)ws;                 ws += (size_t)768 * 256 * 2;
  float*          biasP = (float*)ws;                        ws += 768 * 4;
  __hip_bfloat16* qb  = (__hip_bfloat16*)ws;                 ws += (size_t)kN * 256 * 2;
  __hip_bfloat16* kvb = (__hip_bfloat16*)ws;                 ws += (size_t)kN * 512 * 2;
  int* row_ptr = (int*)ws;                                   ws += ((size_t)(kN + 1) * 4 + 127) & ~127ull;
  i32x2* cv = (i32x2*)ws;

  // merged prep: split_h + build_bt + row_ptr + cv pack in ONE launch
  prep_all_kernel<<<6250 + 768 + 196 + 782, 256, 0, stream>>>(
      h, Ah, Wq, bq, Wk, bk, Wv, bv, Bt, biasP,
      edge_rows, row_ptr, col_ind, val, cv);

  // 391 M-tiles padded to 49 groups of 8; 6 N-tiles; 8 XCD slots
  gemm_qkv_kernel<<<8 * 6 * 49, 256, 0, stream>>>(Ah, Bt, biasP, qb, kvb);

  edge_attn_kernel<<<(kN + 1) / 2, 128, 0, stream>>>(qb, kvb, row_ptr, cv, out);
}